// Round 1
// baseline (13144.879 us; speedup 1.0000x reference)
//
#include <hip/hip_runtime.h>
#include <math.h>

#define S_LEN 4096
#define D_DIM 768
#define M_CNT 1024
#define K_CNT 32
#define MK_CNT 32768
#define H_CNT 8
#define DH_DIM 96
#define CTX_W 10

// ---------------------------------------------------------------- block reduce
__device__ __forceinline__ float block_reduce_sum(float v, float* sbuf) {
#pragma unroll
    for (int off = 32; off; off >>= 1) v += __shfl_down(v, off);
    __syncthreads();                      // protect sbuf reuse across calls
    int wave = threadIdx.x >> 6;
    int lane = threadIdx.x & 63;
    if (lane == 0) sbuf[wave] = v;
    __syncthreads();
    return sbuf[0] + sbuf[1] + sbuf[2] + sbuf[3];
}

// ---------------------------------------------------------------- tiled fp32 GEMM
// C[rows,N] = A[rows,Kd] @ B[Kd,N] (+bias) (optional relu). rows%128==0, N%64==0, Kd%16==0.
#define TM 128
#define TN 64
#define TKG 16

template<bool RELU>
__global__ __launch_bounds__(256) void gemm_f32(
    const float* __restrict__ A, const float* __restrict__ B,
    const float* __restrict__ bias, float* __restrict__ C,
    int rows, int Kd, int N)
{
    __shared__ float As[TKG][TM + 4];
    __shared__ float Bs[TKG][TN];
    const int tid = threadIdx.x;
    const int tx = tid & 15;
    const int ty = tid >> 4;
    const int row0 = blockIdx.y * TM;
    const int col0 = blockIdx.x * TN;

    float acc[8][4];
#pragma unroll
    for (int i = 0; i < 8; ++i)
#pragma unroll
        for (int j = 0; j < 4; ++j) acc[i][j] = 0.f;

    const int ar = tid >> 1;          // 0..127 row in tile
    const int ak = (tid & 1) * 8;     // 0 or 8
    const int bk = tid >> 4;          // 0..15
    const int bn = (tid & 15) * 4;    // 0..60

    for (int k0 = 0; k0 < Kd; k0 += TKG) {
        const float* ap = A + (size_t)(row0 + ar) * Kd + k0 + ak;
        float4 a0 = *(const float4*)ap;
        float4 a1 = *(const float4*)(ap + 4);
        float4 bv = *(const float4*)(B + (size_t)(k0 + bk) * N + col0 + bn);
        As[ak + 0][ar] = a0.x; As[ak + 1][ar] = a0.y; As[ak + 2][ar] = a0.z; As[ak + 3][ar] = a0.w;
        As[ak + 4][ar] = a1.x; As[ak + 5][ar] = a1.y; As[ak + 6][ar] = a1.z; As[ak + 7][ar] = a1.w;
        *(float4*)&Bs[bk][bn] = bv;
        __syncthreads();
#pragma unroll
        for (int kk = 0; kk < TKG; ++kk) {
            const float4* av = (const float4*)&As[kk][ty * 8];
            float4 t0 = av[0], t1 = av[1];
            float4 tb = *(const float4*)&Bs[kk][tx * 4];
            float a[8] = {t0.x, t0.y, t0.z, t0.w, t1.x, t1.y, t1.z, t1.w};
            float b[4] = {tb.x, tb.y, tb.z, tb.w};
#pragma unroll
            for (int i = 0; i < 8; ++i)
#pragma unroll
                for (int j = 0; j < 4; ++j)
                    acc[i][j] = fmaf(a[i], b[j], acc[i][j]);
        }
        __syncthreads();
    }

    float b4[4] = {0.f, 0.f, 0.f, 0.f};
    if (bias) {
        b4[0] = bias[col0 + tx * 4 + 0]; b4[1] = bias[col0 + tx * 4 + 1];
        b4[2] = bias[col0 + tx * 4 + 2]; b4[3] = bias[col0 + tx * 4 + 3];
    }
#pragma unroll
    for (int i = 0; i < 8; ++i) {
        float v0 = acc[i][0] + b4[0], v1 = acc[i][1] + b4[1];
        float v2 = acc[i][2] + b4[2], v3 = acc[i][3] + b4[3];
        if (RELU) {
            v0 = fmaxf(v0, 0.f); v1 = fmaxf(v1, 0.f);
            v2 = fmaxf(v2, 0.f); v3 = fmaxf(v3, 0.f);
        }
        float4 o; o.x = v0; o.y = v1; o.z = v2; o.w = v3;
        *(float4*)(C + (size_t)(row0 + ty * 8 + i) * N + col0 + tx * 4) = o;
    }
}

// ---------------------------------------------------------------- span means
__global__ __launch_bounds__(256) void spans_kernel(
    const float* __restrict__ txt, const int* __restrict__ starts,
    const int* __restrict__ lens, float* __restrict__ mention, float* __restrict__ ctxb)
{
    int m = blockIdx.x;
    int st = starts[m], ln = lens[m];
    int en = st + ln;
    int cs = st - CTX_W; if (cs < 0) cs = 0;
    int ce = en + CTX_W; if (ce > S_LEN - 1) ce = S_LEN - 1;
    int c = threadIdx.x;
    float s0 = 0.f, s1 = 0.f, s2 = 0.f;
    for (int r = st; r <= en; ++r) {
        const float* tr = txt + (size_t)r * D_DIM;
        s0 += tr[c]; s1 += tr[c + 256]; s2 += tr[c + 512];
    }
    float inv = 1.f / (float)(ln + 1);
    float* mp = mention + (size_t)m * D_DIM;
    mp[c] = s0 * inv; mp[c + 256] = s1 * inv; mp[c + 512] = s2 * inv;

    s0 = 0.f; s1 = 0.f; s2 = 0.f;
    for (int r = cs; r < ce; ++r) {
        const float* tr = txt + (size_t)r * D_DIM;
        s0 += tr[c]; s1 += tr[c + 256]; s2 += tr[c + 512];
    }
    inv = 1.f / (float)(ce - cs);
    float* cp = ctxb + (size_t)m * D_DIM;
    cp[c] = s0 * inv; cp[c + 256] = s1 * inv; cp[c + 512] = s2 * inv;
}

// ---------------------------------------------------------------- uni_w2 column-mean
__global__ __launch_bounds__(256) void w2bar_kernel(
    const float* __restrict__ uni_w2, const float* __restrict__ uni_b2,
    float* __restrict__ w2bar, float* __restrict__ b2bar)
{
    __shared__ float sbuf[4];
    int d = blockIdx.x;
    float s = 0.f;
    if (d < D_DIM) {
        for (int j = threadIdx.x; j < D_DIM; j += 256) s += uni_w2[(size_t)d * D_DIM + j];
        s = block_reduce_sum(s, sbuf);
        if (threadIdx.x == 0) w2bar[d] = s * (1.f / (float)D_DIM);
    } else {
        for (int j = threadIdx.x; j < D_DIM; j += 256) s += uni_b2[j];
        s = block_reduce_sum(s, sbuf);
        if (threadIdx.x == 0) *b2bar = s * (1.f / (float)D_DIM);
    }
}

// ---------------------------------------------------------------- 2x2 attention
__global__ __launch_bounds__(512) void attn_kernel(
    const float* __restrict__ qm, const float* __restrict__ km, const float* __restrict__ vm,
    const float* __restrict__ qc, const float* __restrict__ kc, const float* __restrict__ vc,
    float* __restrict__ o, int g0)
{
    int lc = blockIdx.x;
    int gg = g0 + lc;
    int m = gg >> 5;                   // K=32
    int h = threadIdx.x >> 6;
    int lane = threadIdx.x & 63;
    size_t mo = (size_t)m * D_DIM + h * DH_DIM;
    size_t co = (size_t)lc * D_DIM + h * DH_DIM;
    const float* qmr = qm + mo; const float* kmr = km + mo; const float* vmr = vm + mo;
    const float* qcr = qc + co; const float* kcr = kc + co; const float* vcr = vc + co;

    float s00 = 0.f, s01 = 0.f, s10 = 0.f, s11 = 0.f;
    for (int d = lane; d < DH_DIM; d += 64) {
        float a = qmr[d], b = kmr[d], cq = qcr[d], ck = kcr[d];
        s00 += a * b; s01 += a * ck; s10 += cq * b; s11 += cq * ck;
    }
#pragma unroll
    for (int off = 32; off; off >>= 1) {
        s00 += __shfl_down(s00, off); s01 += __shfl_down(s01, off);
        s10 += __shfl_down(s10, off); s11 += __shfl_down(s11, off);
    }
    s00 = __shfl(s00, 0); s01 = __shfl(s01, 0);
    s10 = __shfl(s10, 0); s11 = __shfl(s11, 0);
    const float sc = 0.1020620726159658f;  // 1/sqrt(96)
    s00 *= sc; s01 *= sc; s10 *= sc; s11 *= sc;
    float m0 = fmaxf(s00, s01), m1 = fmaxf(s10, s11);
    float e00 = expf(s00 - m0), e01 = expf(s01 - m0);
    float e10 = expf(s10 - m1), e11 = expf(s11 - m1);
    float i0 = 1.f / (e00 + e01), i1 = 1.f / (e10 + e11);
    float a00 = e00 * i0, a01 = e01 * i0, a10 = e10 * i1, a11 = e11 * i1;

    float* o0 = o + ((size_t)lc * 2) * D_DIM + h * DH_DIM;
    float* o1 = o0 + D_DIM;
    for (int d = lane; d < DH_DIM; d += 64) {
        float a = vmr[d], b = vcr[d];
        o0[d] = a00 * a + a01 * b;
        o1[d] = a10 * a + a11 * b;
    }
}

// ---------------------------------------------------------------- LN (x + pre)
__global__ __launch_bounds__(256) void ln1_kernel(
    const float* __restrict__ pre, const float* __restrict__ mention,
    const float* __restrict__ cand, const float* __restrict__ g,
    const float* __restrict__ b, float* __restrict__ outb, int g0)
{
    __shared__ float sbuf[4];
    int r = blockIdx.x;
    int lc = r >> 1, pos = r & 1;
    int gg = g0 + lc, m = gg >> 5;
    const float* xr = pos ? (cand + (size_t)gg * D_DIM) : (mention + (size_t)m * D_DIM);
    const float* pr = pre + (size_t)r * D_DIM;
    int c = threadIdx.x;
    float v0 = xr[c] + pr[c];
    float v1 = xr[c + 256] + pr[c + 256];
    float v2 = xr[c + 512] + pr[c + 512];
    float mu = block_reduce_sum(v0 + v1 + v2, sbuf) * (1.f / (float)D_DIM);
    float d0 = v0 - mu, d1 = v1 - mu, d2 = v2 - mu;
    float var = block_reduce_sum(d0 * d0 + d1 * d1 + d2 * d2, sbuf) * (1.f / (float)D_DIM);
    float inv = rsqrtf(var + 1e-5f);
    float* op = outb + (size_t)r * D_DIM;
    op[c] = d0 * inv * g[c] + b[c];
    op[c + 256] = d1 * inv * g[c + 256] + b[c + 256];
    op[c + 512] = d2 * inv * g[c + 512] + b[c + 512];
}

__global__ __launch_bounds__(256) void ln2_kernel(
    const float* __restrict__ pre, const float* __restrict__ resid,
    const float* __restrict__ g, const float* __restrict__ b,
    float* __restrict__ outb)
{
    __shared__ float sbuf[4];
    int r = blockIdx.x;
    const float* xr = resid + (size_t)r * D_DIM;
    const float* pr = pre + (size_t)r * D_DIM;
    int c = threadIdx.x;
    float v0 = xr[c] + pr[c];
    float v1 = xr[c + 256] + pr[c + 256];
    float v2 = xr[c + 512] + pr[c + 512];
    float mu = block_reduce_sum(v0 + v1 + v2, sbuf) * (1.f / (float)D_DIM);
    float d0 = v0 - mu, d1 = v1 - mu, d2 = v2 - mu;
    float var = block_reduce_sum(d0 * d0 + d1 * d1 + d2 * d2, sbuf) * (1.f / (float)D_DIM);
    float inv = rsqrtf(var + 1e-5f);
    float* op = outb + (size_t)r * D_DIM;
    op[c] = d0 * inv * g[c] + b[c];
    op[c + 256] = d1 * inv * g[c + 256] + b[c + 256];
    op[c + 512] = d2 * inv * g[c + 512] + b[c + 512];
}

// ---------------------------------------------------------------- output heads
__global__ __launch_bounds__(256) void atg_kernel(
    const float* __restrict__ x2, float* __restrict__ out, int g0)
{
    __shared__ float sbuf[4];
    int lc = blockIdx.x;
    int gg = g0 + lc;
    const float* e0 = x2 + (size_t)(lc * 2) * D_DIM;
    const float* e1 = e0 + D_DIM;
    float d = 0.f, a = 0.f, bb = 0.f;
    for (int c = threadIdx.x; c < D_DIM; c += 256) {
        float u = e0[c], w = e1[c];
        d += u * w; a += u * u; bb += w * w;
    }
    d = block_reduce_sum(d, sbuf);
    a = block_reduce_sum(a, sbuf);
    bb = block_reduce_sum(bb, sbuf);
    if (threadIdx.x == 0) {
        float n0 = fmaxf(sqrtf(a), 1e-8f);
        float n1 = fmaxf(sqrtf(bb), 1e-8f);
        out[MK_CNT + gg] = d / (n0 * n1);
    }
}

__global__ __launch_bounds__(256) void relik_kernel(
    const float* __restrict__ Ar, const float* __restrict__ Br,
    const float* __restrict__ w2, const float* __restrict__ b2,
    float* __restrict__ out, int g0)
{
    __shared__ float sbuf[4];
    int lc = blockIdx.x;
    int gg = g0 + lc, m = gg >> 5;
    const float* ar = Ar + (size_t)m * D_DIM;
    const float* br = Br + (size_t)lc * D_DIM;
    float s = 0.f;
    for (int c = threadIdx.x; c < D_DIM; c += 256) {
        float h = fmaxf(ar[c] + br[c], 0.f);   // bias already folded into Ar
        s += h * w2[c];
    }
    s = block_reduce_sum(s, sbuf);
    if (threadIdx.x == 0) out[gg] = s + b2[0];
}

__global__ __launch_bounds__(256) void uni_kernel(
    const float* __restrict__ Au, const float* __restrict__ Bu,
    const float* __restrict__ w2bar, const float* __restrict__ b2bar,
    float* __restrict__ out, int g0)
{
    __shared__ float sbuf[4];
    int lc = blockIdx.x;
    int gg = g0 + lc, m = gg >> 5;
    const float* ar = Au + (size_t)m * D_DIM;
    const float* br = Bu + (size_t)lc * D_DIM;
    float s = 0.f;
    for (int c = threadIdx.x; c < D_DIM; c += 256) {
        float h = fmaxf(ar[c] + br[c], 0.f);
        s += h * w2bar[c];
    }
    s = block_reduce_sum(s, sbuf);
    if (threadIdx.x == 0) {
        float z = s + *b2bar;
        out[2 * MK_CNT + gg] = 1.f / (1.f + expf(-z));
    }
}

// ---------------------------------------------------------------- host
static inline void launch_gemm(const float* A, const float* B, const float* bias, float* C,
                               int rows, int Kd, int N, bool relu, hipStream_t st) {
    dim3 grid(N / TN, rows / TM);
    if (relu) gemm_f32<true><<<grid, 256, 0, st>>>(A, B, bias, C, rows, Kd, N);
    else      gemm_f32<false><<<grid, 256, 0, st>>>(A, B, bias, C, rows, Kd, N);
}

extern "C" void kernel_launch(void* const* d_in, const int* in_sizes, int n_in,
                              void* d_out, int out_size, void* d_ws, size_t ws_size,
                              hipStream_t stream) {
    const float* text     = (const float*)d_in[0];
    const float* cand     = (const float*)d_in[1];
    const int*   starts   = (const int*)d_in[2];
    const int*   lens     = (const int*)d_in[3];
    const float* relik_w1 = (const float*)d_in[4];
    const float* relik_b1 = (const float*)d_in[5];
    const float* relik_w2 = (const float*)d_in[6];
    const float* relik_b2 = (const float*)d_in[7];
    const float* wq = (const float*)d_in[8];
    const float* bq = (const float*)d_in[9];
    const float* wk = (const float*)d_in[10];
    const float* bk = (const float*)d_in[11];
    const float* wv = (const float*)d_in[12];
    const float* bv = (const float*)d_in[13];
    const float* wo = (const float*)d_in[14];
    const float* bo = (const float*)d_in[15];
    const float* ln1_g = (const float*)d_in[16];
    const float* ln1_b = (const float*)d_in[17];
    const float* ffn_w1 = (const float*)d_in[18];
    const float* ffn_b1 = (const float*)d_in[19];
    const float* ffn_w2 = (const float*)d_in[20];
    const float* ffn_b2 = (const float*)d_in[21];
    const float* ln2_g = (const float*)d_in[22];
    const float* ln2_b = (const float*)d_in[23];
    const float* uni_w1 = (const float*)d_in[24];
    const float* uni_b1 = (const float*)d_in[25];
    const float* uni_w2 = (const float*)d_in[26];
    const float* uni_b2 = (const float*)d_in[27];
    float* out = (float*)d_out;

    const size_t MD = (size_t)M_CNT * D_DIM;

    // pick chunk size NC (candidate rows per chunk) so workspace fits:
    // fixed: 7*MD + 832 floats; per-chunk: 19*NC*768 floats
    size_t fixed_f = 7 * MD + 832;
    int NC = 4096;
    while (NC > 128 && (fixed_f + (size_t)19 * NC * D_DIM) * 4 > ws_size) NC >>= 1;
    const size_t NCD = (size_t)NC * D_DIM;

    float* p = (float*)d_ws;
    float* mention = p; p += MD;
    float* ctxb    = p; p += MD;
    float* qm      = p; p += MD;
    float* km      = p; p += MD;
    float* vm      = p; p += MD;
    float* Ar      = p; p += MD;
    float* Au      = p; p += MD;
    float* w2bar   = p; p += 768;
    float* b2bar   = p; p += 64;
    float* qcb = p; p += NCD;
    float* kcb = p; p += NCD;
    float* vcb = p; p += NCD;
    float* Brl = p; p += NCD;
    float* Bun = p; p += NCD;
    float* obuf = p; p += 2 * NCD;
    float* x1b  = p; p += 2 * NCD;
    float* x2b  = p; p += 2 * NCD;
    float* hb   = p; p += 8 * NCD;

    // ---- setup (per-m) ----
    spans_kernel<<<M_CNT, 256, 0, stream>>>(text, starts, lens, mention, ctxb);
    w2bar_kernel<<<D_DIM + 1, 256, 0, stream>>>(uni_w2, uni_b2, w2bar, b2bar);

    launch_gemm(mention, wq, bq, qm, M_CNT, D_DIM, D_DIM, false, stream);
    launch_gemm(mention, wk, bk, km, M_CNT, D_DIM, D_DIM, false, stream);
    launch_gemm(mention, wv, bv, vm, M_CNT, D_DIM, D_DIM, false, stream);
    launch_gemm(mention, relik_w1, relik_b1, Ar, M_CNT, D_DIM, D_DIM, false, stream);
    launch_gemm(ctxb, uni_w1, uni_b1, Au, M_CNT, D_DIM, D_DIM, false, stream);

    const float* relik_w1b = relik_w1 + (size_t)D_DIM * D_DIM;
    const float* uni_w1b   = uni_w1 + (size_t)D_DIM * D_DIM;

    int nch = MK_CNT / NC;
    for (int c = 0; c < nch; ++c) {
        int g0 = c * NC;
        const float* cc = cand + (size_t)g0 * D_DIM;
        launch_gemm(cc, wq, bq, qcb, NC, D_DIM, D_DIM, false, stream);
        launch_gemm(cc, wk, bk, kcb, NC, D_DIM, D_DIM, false, stream);
        launch_gemm(cc, wv, bv, vcb, NC, D_DIM, D_DIM, false, stream);
        launch_gemm(cc, relik_w1b, nullptr, Brl, NC, D_DIM, D_DIM, false, stream);
        launch_gemm(cc, uni_w1b, nullptr, Bun, NC, D_DIM, D_DIM, false, stream);

        attn_kernel<<<NC, 512, 0, stream>>>(qm, km, vm, qcb, kcb, vcb, obuf, g0);

        launch_gemm(obuf, wo, bo, x1b, 2 * NC, D_DIM, D_DIM, false, stream);
        ln1_kernel<<<2 * NC, 256, 0, stream>>>(x1b, mention, cand, ln1_g, ln1_b, x1b, g0);

        launch_gemm(x1b, ffn_w1, ffn_b1, hb, 2 * NC, D_DIM, 4 * D_DIM, true, stream);
        launch_gemm(hb, ffn_w2, ffn_b2, x2b, 2 * NC, 4 * D_DIM, D_DIM, false, stream);
        ln2_kernel<<<2 * NC, 256, 0, stream>>>(x2b, x1b, ln2_g, ln2_b, x2b);

        atg_kernel<<<NC, 256, 0, stream>>>(x2b, out, g0);
        relik_kernel<<<NC, 256, 0, stream>>>(Ar, Brl, relik_w2, relik_b2, out, g0);
        uni_kernel<<<NC, 256, 0, stream>>>(Au, Bun, w2bar, b2bar, out, g0);
    }
}

// Round 2
// 2325.954 us; speedup vs baseline: 5.6514x; 5.6514x over previous
//
#include <hip/hip_runtime.h>
#include <math.h>

#define S_LEN 4096
#define D_DIM 768
#define M_CNT 1024
#define K_CNT 32
#define MK_CNT 32768
#define DH_DIM 96
#define CTX_W 10

typedef __bf16 bf16_t;
typedef bf16_t bf16x8 __attribute__((ext_vector_type(8)));
typedef float f32x4 __attribute__((ext_vector_type(4)));

// ---------------------------------------------------------------- block reduce
__device__ __forceinline__ float block_reduce_sum(float v, float* sbuf) {
#pragma unroll
    for (int off = 32; off; off >>= 1) v += __shfl_down(v, off);
    __syncthreads();
    int wave = threadIdx.x >> 6;
    int lane = threadIdx.x & 63;
    if (lane == 0) sbuf[wave] = v;
    __syncthreads();
    return sbuf[0] + sbuf[1] + sbuf[2] + sbuf[3];
}

// ---------------------------------------------------------------- bf16 MFMA GEMM
// C[rows,N] = A[rows,Kd] @ Bt[N,Kd]^T (+bias)(+relu). rows%128==0, N%128==0, Kd%64==0.
// A, Bt bf16; C fp32 or bf16. m97 structure: 128x128 tile, BK=64,
// global_load_lds width=16, XOR-swizzled source chunks for conflict-free ds_read_b128.
template<int OUT_BF16, int RELU>
__global__ __launch_bounds__(256, 2) void gemm_mfma(
    const bf16_t* __restrict__ A, const bf16_t* __restrict__ Bt,
    const float* __restrict__ bias, void* __restrict__ C,
    int Kd, int N)
{
    __shared__ bf16_t As[128 * 64];
    __shared__ bf16_t Bs[128 * 64];
    const int tid = threadIdx.x;
    const int w = tid >> 6, l = tid & 63;
    const int row0 = blockIdx.y * 128, col0 = blockIdx.x * 128;

    // staging: per call c (of 4), wave w covers 8 rows; lane l -> row srow+c*32, 16B chunk gchunk
    const int srow = w * 8 + (l >> 3);
    const int gchunk = (l & 7) ^ ((l >> 3) & 7);     // XOR swizzle (slot order fixed by HW)
    const bf16_t* gA = A + (size_t)(row0 + srow) * Kd + gchunk * 8;
    const bf16_t* gB = Bt + (size_t)(col0 + srow) * Kd + gchunk * 8;

    const int wm = w >> 1, wn = w & 1;               // 2x2 wave grid, 64x64 each
    f32x4 acc[4][4] = {};

    for (int k0 = 0; k0 < Kd; k0 += 64) {
#pragma unroll
        for (int c = 0; c < 4; ++c) {
            __builtin_amdgcn_global_load_lds(
                (const __attribute__((address_space(1))) void*)(gA + (size_t)(c * 32) * Kd + k0),
                (__attribute__((address_space(3))) void*)(As + (c * 256 + w * 64) * 8), 16, 0, 0);
            __builtin_amdgcn_global_load_lds(
                (const __attribute__((address_space(1))) void*)(gB + (size_t)(c * 32) * Kd + k0),
                (__attribute__((address_space(3))) void*)(Bs + (c * 256 + w * 64) * 8), 16, 0, 0);
        }
        __syncthreads();
#pragma unroll
        for (int ks = 0; ks < 2; ++ks) {
            bf16x8 af[4], bfr[4];
#pragma unroll
            for (int i = 0; i < 4; ++i) {
                int arow = wm * 64 + i * 16 + (l & 15);
                int slot = (ks * 4 + (l >> 4)) ^ (l & 7);
                af[i] = *(const bf16x8*)(As + arow * 64 + slot * 8);
                int brow = wn * 64 + i * 16 + (l & 15);
                bfr[i] = *(const bf16x8*)(Bs + brow * 64 + slot * 8);
            }
#pragma unroll
            for (int i = 0; i < 4; ++i)
#pragma unroll
                for (int j = 0; j < 4; ++j)
                    acc[i][j] = __builtin_amdgcn_mfma_f32_16x16x32_bf16(af[i], bfr[j], acc[i][j], 0, 0, 0);
        }
        __syncthreads();
    }

#pragma unroll
    for (int i = 0; i < 4; ++i) {
        int row = row0 + wm * 64 + i * 16 + (l >> 4) * 4;
#pragma unroll
        for (int j = 0; j < 4; ++j) {
            int col = col0 + wn * 64 + j * 16 + (l & 15);
            float bv = bias ? bias[col] : 0.f;
#pragma unroll
            for (int r = 0; r < 4; ++r) {
                float v = acc[i][j][r] + bv;
                if (RELU) v = fmaxf(v, 0.f);
                if (OUT_BF16) ((bf16_t*)C)[(size_t)(row + r) * N + col] = (bf16_t)v;
                else          ((float*)C)[(size_t)(row + r) * N + col] = v;
            }
        }
    }
}

static inline void launch_gemm(const bf16_t* A, const bf16_t* Bt, const float* bias, void* C,
                               int rows, int Kd, int N, bool relu, bool outbf, hipStream_t st) {
    dim3 grid(N / 128, rows / 128);
    if (outbf) {
        if (relu) gemm_mfma<1, 1><<<grid, 256, 0, st>>>(A, Bt, bias, C, Kd, N);
        else      gemm_mfma<1, 0><<<grid, 256, 0, st>>>(A, Bt, bias, C, Kd, N);
    } else {
        if (relu) gemm_mfma<0, 1><<<grid, 256, 0, st>>>(A, Bt, bias, C, Kd, N);
        else      gemm_mfma<0, 0><<<grid, 256, 0, st>>>(A, Bt, bias, C, Kd, N);
    }
}

// ---------------------------------------------------------------- transpose fp32 W[Kd][N] -> bf16 Wt[N][Kd]
__global__ __launch_bounds__(256) void transpose_bf16(
    const float* __restrict__ W, bf16_t* __restrict__ Wt, int Kd, int N)
{
    __shared__ float t[32][33];
    int bx = blockIdx.x * 32, by = blockIdx.y * 32;
    int x = threadIdx.x & 31, y = threadIdx.x >> 5;
#pragma unroll
    for (int yy = y; yy < 32; yy += 8) t[yy][x] = W[(size_t)(by + yy) * N + bx + x];
    __syncthreads();
#pragma unroll
    for (int yy = y; yy < 32; yy += 8) Wt[(size_t)(bx + yy) * Kd + by + x] = (bf16_t)t[x][yy];
}

// ---------------------------------------------------------------- fp32 -> bf16 (vectorized)
__global__ __launch_bounds__(256) void cvt_bf16(
    const float* __restrict__ x, bf16_t* __restrict__ y, int n4)
{
    int i = blockIdx.x * 256 + threadIdx.x;
    if (i < n4) {
        float4 v = ((const float4*)x)[i];
        bf16_t o4[4] = {(bf16_t)v.x, (bf16_t)v.y, (bf16_t)v.z, (bf16_t)v.w};
        ((uint2*)y)[i] = *(uint2*)o4;
    }
}

// ---------------------------------------------------------------- bias pack [bq|bk|bv]
__global__ __launch_bounds__(256) void pack_bias(
    const float* __restrict__ bq, const float* __restrict__ bk,
    const float* __restrict__ bv, float* __restrict__ o)
{
    int i = blockIdx.x * 256 + threadIdx.x;
    if (i < D_DIM) { o[i] = bq[i]; o[i + 768] = bk[i]; o[i + 1536] = bv[i]; }
}

// ---------------------------------------------------------------- span means (fp32 + bf16 out)
__global__ __launch_bounds__(256) void spans_kernel(
    const float* __restrict__ txt, const int* __restrict__ starts,
    const int* __restrict__ lens, float* __restrict__ mention,
    bf16_t* __restrict__ mentionb, bf16_t* __restrict__ ctxb)
{
    int m = blockIdx.x;
    int st = starts[m], ln = lens[m];
    int en = st + ln;
    int cs = st - CTX_W; if (cs < 0) cs = 0;
    int ce = en + CTX_W; if (ce > S_LEN - 1) ce = S_LEN - 1;
    int c = threadIdx.x;
    float s0 = 0.f, s1 = 0.f, s2 = 0.f;
    for (int r = st; r <= en; ++r) {
        const float* tr = txt + (size_t)r * D_DIM;
        s0 += tr[c]; s1 += tr[c + 256]; s2 += tr[c + 512];
    }
    float inv = 1.f / (float)(ln + 1);
    float* mp = mention + (size_t)m * D_DIM;
    bf16_t* mb = mentionb + (size_t)m * D_DIM;
    mp[c] = s0 * inv; mp[c + 256] = s1 * inv; mp[c + 512] = s2 * inv;
    mb[c] = (bf16_t)(s0 * inv); mb[c + 256] = (bf16_t)(s1 * inv); mb[c + 512] = (bf16_t)(s2 * inv);

    s0 = 0.f; s1 = 0.f; s2 = 0.f;
    for (int r = cs; r < ce; ++r) {
        const float* tr = txt + (size_t)r * D_DIM;
        s0 += tr[c]; s1 += tr[c + 256]; s2 += tr[c + 512];
    }
    inv = 1.f / (float)(ce - cs);
    bf16_t* cp = ctxb + (size_t)m * D_DIM;
    cp[c] = (bf16_t)(s0 * inv); cp[c + 256] = (bf16_t)(s1 * inv); cp[c + 512] = (bf16_t)(s2 * inv);
}

// ---------------------------------------------------------------- uni_w2 column-mean
__global__ __launch_bounds__(256) void w2bar_kernel(
    const float* __restrict__ uni_w2, const float* __restrict__ uni_b2,
    float* __restrict__ w2bar, float* __restrict__ b2bar)
{
    __shared__ float sbuf[4];
    int d = blockIdx.x;
    float s = 0.f;
    if (d < D_DIM) {
        for (int j = threadIdx.x; j < D_DIM; j += 256) s += uni_w2[(size_t)d * D_DIM + j];
        s = block_reduce_sum(s, sbuf);
        if (threadIdx.x == 0) w2bar[d] = s * (1.f / (float)D_DIM);
    } else {
        for (int j = threadIdx.x; j < D_DIM; j += 256) s += uni_b2[j];
        s = block_reduce_sum(s, sbuf);
        if (threadIdx.x == 0) *b2bar = s * (1.f / (float)D_DIM);
    }
}

// ---------------------------------------------------------------- 2x2 attention (packed bf16 QKV)
__global__ __launch_bounds__(512) void attn_kernel(
    const bf16_t* __restrict__ qkvm, const bf16_t* __restrict__ qkvc,
    bf16_t* __restrict__ o, int g0)
{
    int lc = blockIdx.x;
    int gg = g0 + lc;
    int m = gg >> 5;
    int h = threadIdx.x >> 6;
    int lane = threadIdx.x & 63;
    const bf16_t* bm = qkvm + (size_t)m * 2304 + h * DH_DIM;
    const bf16_t* bc = qkvc + (size_t)lc * 2304 + h * DH_DIM;

    float s00 = 0.f, s01 = 0.f, s10 = 0.f, s11 = 0.f;
    for (int d = lane; d < DH_DIM; d += 64) {
        float qmv = (float)bm[d], kmv = (float)bm[d + 768];
        float qcv = (float)bc[d], kcv = (float)bc[d + 768];
        s00 += qmv * kmv; s01 += qmv * kcv; s10 += qcv * kmv; s11 += qcv * kcv;
    }
#pragma unroll
    for (int off = 32; off; off >>= 1) {
        s00 += __shfl_down(s00, off); s01 += __shfl_down(s01, off);
        s10 += __shfl_down(s10, off); s11 += __shfl_down(s11, off);
    }
    s00 = __shfl(s00, 0); s01 = __shfl(s01, 0);
    s10 = __shfl(s10, 0); s11 = __shfl(s11, 0);
    const float sc = 0.1020620726159658f;  // 1/sqrt(96)
    s00 *= sc; s01 *= sc; s10 *= sc; s11 *= sc;
    float m0 = fmaxf(s00, s01), m1 = fmaxf(s10, s11);
    float e00 = expf(s00 - m0), e01 = expf(s01 - m0);
    float e10 = expf(s10 - m1), e11 = expf(s11 - m1);
    float i0 = 1.f / (e00 + e01), i1 = 1.f / (e10 + e11);
    float a00 = e00 * i0, a01 = e01 * i0, a10 = e10 * i1, a11 = e11 * i1;

    bf16_t* o0 = o + ((size_t)lc * 2) * D_DIM + h * DH_DIM;
    bf16_t* o1 = o0 + D_DIM;
    for (int d = lane; d < DH_DIM; d += 64) {
        float vmv = (float)bm[d + 1536], vcv = (float)bc[d + 1536];
        o0[d] = (bf16_t)(a00 * vmv + a01 * vcv);
        o1[d] = (bf16_t)(a10 * vmv + a11 * vcv);
    }
}

// ---------------------------------------------------------------- LN1: x1 = LN(x + pre); out fp32 + bf16
__global__ __launch_bounds__(256) void ln1_kernel(
    const float* __restrict__ pre, const float* __restrict__ mention,
    const float* __restrict__ cand, const float* __restrict__ g,
    const float* __restrict__ b, float* __restrict__ x1f,
    bf16_t* __restrict__ x1b, int g0)
{
    __shared__ float sbuf[4];
    int r = blockIdx.x;
    int lc = r >> 1, pos = r & 1;
    int gg = g0 + lc, m = gg >> 5;
    const float* xr = pos ? (cand + (size_t)gg * D_DIM) : (mention + (size_t)m * D_DIM);
    const float* pr = pre + (size_t)r * D_DIM;
    int c = threadIdx.x;
    float v0 = xr[c] + pr[c];
    float v1 = xr[c + 256] + pr[c + 256];
    float v2 = xr[c + 512] + pr[c + 512];
    float mu = block_reduce_sum(v0 + v1 + v2, sbuf) * (1.f / (float)D_DIM);
    float d0 = v0 - mu, d1 = v1 - mu, d2 = v2 - mu;
    float var = block_reduce_sum(d0 * d0 + d1 * d1 + d2 * d2, sbuf) * (1.f / (float)D_DIM);
    float inv = rsqrtf(var + 1e-5f);
    float o0 = d0 * inv * g[c] + b[c];
    float o1 = d1 * inv * g[c + 256] + b[c + 256];
    float o2 = d2 * inv * g[c + 512] + b[c + 512];
    float* fp = x1f + (size_t)r * D_DIM;
    bf16_t* bp = x1b + (size_t)r * D_DIM;
    fp[c] = o0; fp[c + 256] = o1; fp[c + 512] = o2;
    bp[c] = (bf16_t)o0; bp[c + 256] = (bf16_t)o1; bp[c + 512] = (bf16_t)o2;
}

// ---------------------------------------------------------------- LN2 (in place over pre)
__global__ __launch_bounds__(256) void ln2_kernel(
    float* __restrict__ pre, const float* __restrict__ resid,
    const float* __restrict__ g, const float* __restrict__ b)
{
    __shared__ float sbuf[4];
    int r = blockIdx.x;
    const float* xr = resid + (size_t)r * D_DIM;
    float* pr = pre + (size_t)r * D_DIM;
    int c = threadIdx.x;
    float v0 = xr[c] + pr[c];
    float v1 = xr[c + 256] + pr[c + 256];
    float v2 = xr[c + 512] + pr[c + 512];
    float mu = block_reduce_sum(v0 + v1 + v2, sbuf) * (1.f / (float)D_DIM);
    float d0 = v0 - mu, d1 = v1 - mu, d2 = v2 - mu;
    float var = block_reduce_sum(d0 * d0 + d1 * d1 + d2 * d2, sbuf) * (1.f / (float)D_DIM);
    float inv = rsqrtf(var + 1e-5f);
    pr[c] = d0 * inv * g[c] + b[c];
    pr[c + 256] = d1 * inv * g[c + 256] + b[c + 256];
    pr[c + 512] = d2 * inv * g[c + 512] + b[c + 512];
}

// ---------------------------------------------------------------- output heads
__global__ __launch_bounds__(256) void atg_kernel(
    const float* __restrict__ x2, float* __restrict__ out, int g0)
{
    __shared__ float sbuf[4];
    int lc = blockIdx.x;
    int gg = g0 + lc;
    const float* e0 = x2 + (size_t)(lc * 2) * D_DIM;
    const float* e1 = e0 + D_DIM;
    float d = 0.f, a = 0.f, bb = 0.f;
    for (int c = threadIdx.x; c < D_DIM; c += 256) {
        float u = e0[c], w = e1[c];
        d += u * w; a += u * u; bb += w * w;
    }
    d = block_reduce_sum(d, sbuf);
    a = block_reduce_sum(a, sbuf);
    bb = block_reduce_sum(bb, sbuf);
    if (threadIdx.x == 0) {
        float n0 = fmaxf(sqrtf(a), 1e-8f);
        float n1 = fmaxf(sqrtf(bb), 1e-8f);
        out[MK_CNT + gg] = d / (n0 * n1);
    }
}

__global__ __launch_bounds__(256) void relik_kernel(
    const float* __restrict__ Ar, const bf16_t* __restrict__ bb,
    const float* __restrict__ w2, const float* __restrict__ b2,
    float* __restrict__ out, int g0)
{
    __shared__ float sbuf[4];
    int lc = blockIdx.x;
    int gg = g0 + lc, m = gg >> 5;
    const float* ar = Ar + (size_t)m * D_DIM;
    const bf16_t* br = bb + (size_t)lc * 1536;
    float s = 0.f;
    for (int c = threadIdx.x; c < D_DIM; c += 256) {
        float h = fmaxf(ar[c] + (float)br[c], 0.f);
        s += h * w2[c];
    }
    s = block_reduce_sum(s, sbuf);
    if (threadIdx.x == 0) out[gg] = s + b2[0];
}

__global__ __launch_bounds__(256) void uni_kernel(
    const float* __restrict__ Au, const bf16_t* __restrict__ bb,
    const float* __restrict__ w2bar, const float* __restrict__ b2bar,
    float* __restrict__ out, int g0)
{
    __shared__ float sbuf[4];
    int lc = blockIdx.x;
    int gg = g0 + lc, m = gg >> 5;
    const float* ar = Au + (size_t)m * D_DIM;
    const bf16_t* br = bb + (size_t)lc * 1536 + 768;
    float s = 0.f;
    for (int c = threadIdx.x; c < D_DIM; c += 256) {
        float h = fmaxf(ar[c] + (float)br[c], 0.f);
        s += h * w2bar[c];
    }
    s = block_reduce_sum(s, sbuf);
    if (threadIdx.x == 0) {
        float z = s + *b2bar;
        out[2 * MK_CNT + gg] = 1.f / (1.f + expf(-z));
    }
}

// ---------------------------------------------------------------- host
extern "C" void kernel_launch(void* const* d_in, const int* in_sizes, int n_in,
                              void* d_out, int out_size, void* d_ws, size_t ws_size,
                              hipStream_t stream) {
    const float* text     = (const float*)d_in[0];
    const float* cand     = (const float*)d_in[1];
    const int*   starts   = (const int*)d_in[2];
    const int*   lens     = (const int*)d_in[3];
    const float* relik_w1 = (const float*)d_in[4];
    const float* relik_b1 = (const float*)d_in[5];
    const float* relik_w2 = (const float*)d_in[6];
    const float* relik_b2 = (const float*)d_in[7];
    const float* wq = (const float*)d_in[8];
    const float* bq = (const float*)d_in[9];
    const float* wk = (const float*)d_in[10];
    const float* bk = (const float*)d_in[11];
    const float* wv = (const float*)d_in[12];
    const float* bv = (const float*)d_in[13];
    const float* wo = (const float*)d_in[14];
    const float* bo = (const float*)d_in[15];
    const float* ln1_g = (const float*)d_in[16];
    const float* ln1_b = (const float*)d_in[17];
    const float* ffn_w1 = (const float*)d_in[18];
    const float* ffn_b1 = (const float*)d_in[19];
    const float* ffn_w2 = (const float*)d_in[20];
    const float* ffn_b2 = (const float*)d_in[21];
    const float* ln2_g = (const float*)d_in[22];
    const float* ln2_b = (const float*)d_in[23];
    const float* uni_w1 = (const float*)d_in[24];
    const float* uni_b1 = (const float*)d_in[25];
    const float* uni_w2 = (const float*)d_in[26];
    const float* uni_b2 = (const float*)d_in[27];
    float* out = (float*)d_out;

    const size_t MD = (size_t)M_CNT * D_DIM;
    const size_t DD = (size_t)D_DIM * D_DIM;

    // fixed workspace: 21,630,016 floats; per chunk: NC*9600 floats
    size_t fixed_f = 21700000;
    int NC = 4096;
    while (NC > 128 && (fixed_f + (size_t)NC * 9600) * 4 > ws_size) NC >>= 1;
    const size_t NCD = (size_t)NC * D_DIM;

    float* p = (float*)d_ws;
    float* mention = p; p += MD;                    // fp32 residual
    float* Ar      = p; p += MD;                    // mention @ relik_w1a + b1
    float* Au      = p; p += MD;                    // ctx @ uni_w1a + b1
    float* bqkv    = p; p += 2304;
    float* w2bar   = p; p += 768;
    float* b2bar   = p; p += 64;
    bf16_t* mentionb = (bf16_t*)p; p += MD / 2;
    bf16_t* ctxb     = (bf16_t*)p; p += MD / 2;
    bf16_t* qkvm     = (bf16_t*)p; p += (size_t)M_CNT * 2304 / 2;
    bf16_t* wqkvT    = (bf16_t*)p; p += 3 * DD / 2;
    bf16_t* woT      = (bf16_t*)p; p += DD / 2;
    bf16_t* relikAT  = (bf16_t*)p; p += DD / 2;
    bf16_t* uniAT    = (bf16_t*)p; p += DD / 2;
    bf16_t* ruT      = (bf16_t*)p; p += 2 * DD / 2;
    bf16_t* ffn_w1T  = (bf16_t*)p; p += 4 * DD / 2;
    bf16_t* ffn_w2T  = (bf16_t*)p; p += 4 * DD / 2;
    bf16_t* candb    = (bf16_t*)p; p += (size_t)MK_CNT * D_DIM / 2;
    // per-chunk
    bf16_t* qkvc  = (bf16_t*)p; p += (size_t)NC * 2304 / 2;
    bf16_t* bb    = (bf16_t*)p; p += (size_t)NC * 1536 / 2;
    bf16_t* obuf  = (bf16_t*)p; p += 2 * NCD / 2;
    bf16_t* x1b   = (bf16_t*)p; p += 2 * NCD / 2;
    bf16_t* hb    = (bf16_t*)p; p += (size_t)2 * NC * 3072 / 2;
    float*  x1f   = p; p += 2 * NCD;               // also the wo-GEMM output (pre-LN1)
    float*  x2f   = p; p += 2 * NCD;               // FFN2 out, then LN2 in place

    // ---- weight prep ----
    dim3 t768(768 / 32, 768 / 32);
    transpose_bf16<<<t768, 256, 0, stream>>>(wq, wqkvT, 768, 768);
    transpose_bf16<<<t768, 256, 0, stream>>>(wk, wqkvT + DD, 768, 768);
    transpose_bf16<<<t768, 256, 0, stream>>>(wv, wqkvT + 2 * DD, 768, 768);
    transpose_bf16<<<t768, 256, 0, stream>>>(wo, woT, 768, 768);
    transpose_bf16<<<t768, 256, 0, stream>>>(relik_w1, relikAT, 768, 768);
    transpose_bf16<<<t768, 256, 0, stream>>>(relik_w1 + DD, ruT, 768, 768);
    transpose_bf16<<<t768, 256, 0, stream>>>(uni_w1, uniAT, 768, 768);
    transpose_bf16<<<t768, 256, 0, stream>>>(uni_w1 + DD, ruT + DD, 768, 768);
    transpose_bf16<<<dim3(3072 / 32, 768 / 32), 256, 0, stream>>>(ffn_w1, ffn_w1T, 768, 3072);
    transpose_bf16<<<dim3(768 / 32, 3072 / 32), 256, 0, stream>>>(ffn_w2, ffn_w2T, 3072, 768);
    pack_bias<<<3, 256, 0, stream>>>(bq, bk, bv, bqkv);
    w2bar_kernel<<<D_DIM + 1, 256, 0, stream>>>(uni_w2, uni_b2, w2bar, b2bar);
    cvt_bf16<<<(MK_CNT * D_DIM / 4 + 255) / 256, 256, 0, stream>>>(cand, candb, MK_CNT * D_DIM / 4);

    // ---- per-mention precompute ----
    spans_kernel<<<M_CNT, 256, 0, stream>>>(text, starts, lens, mention, mentionb, ctxb);
    launch_gemm(mentionb, wqkvT, bqkv, qkvm, M_CNT, 768, 2304, false, true, stream);
    launch_gemm(mentionb, relikAT, relik_b1, Ar, M_CNT, 768, 768, false, false, stream);
    launch_gemm(ctxb, uniAT, uni_b1, Au, M_CNT, 768, 768, false, false, stream);

    int nch = MK_CNT / NC;
    for (int c = 0; c < nch; ++c) {
        int g0 = c * NC;
        const bf16_t* cc = candb + (size_t)g0 * D_DIM;
        launch_gemm(cc, wqkvT, bqkv, qkvc, NC, 768, 2304, false, true, stream);
        launch_gemm(cc, ruT, nullptr, bb, NC, 768, 1536, false, true, stream);

        attn_kernel<<<NC, 512, 0, stream>>>(qkvm, qkvc, obuf, g0);

        launch_gemm(obuf, woT, bo, x1f, 2 * NC, 768, 768, false, false, stream);
        ln1_kernel<<<2 * NC, 256, 0, stream>>>(x1f, mention, cand, ln1_g, ln1_b, x1f, x1b, g0);

        launch_gemm(x1b, ffn_w1T, ffn_b1, hb, 2 * NC, 768, 3072, true, true, stream);
        launch_gemm(hb, ffn_w2T, ffn_b2, x2f, 2 * NC, 3072, 768, false, false, stream);
        ln2_kernel<<<2 * NC, 256, 0, stream>>>(x2f, x1f, ln2_g, ln2_b);

        atg_kernel<<<NC, 256, 0, stream>>>(x2f, out, g0);
        relik_kernel<<<NC, 256, 0, stream>>>(Ar, bb, relik_w2, relik_b2, out, g0);
        uni_kernel<<<NC, 256, 0, stream>>>(Au, bb, w2bar, b2bar, out, g0);
    }
}

// Round 3
// 1710.909 us; speedup vs baseline: 7.6830x; 1.3595x over previous
//
#include <hip/hip_runtime.h>
#include <math.h>

#define S_LEN 4096
#define D_DIM 768
#define M_CNT 1024
#define K_CNT 32
#define MK_CNT 32768
#define DH_DIM 96
#define CTX_W 10

typedef __bf16 bf16_t;
typedef bf16_t bf16x8 __attribute__((ext_vector_type(8)));
typedef float f32x4 __attribute__((ext_vector_type(4)));
typedef float f32x16 __attribute__((ext_vector_type(16)));
typedef int i32x4 __attribute__((ext_vector_type(4)));
typedef int i32x8 __attribute__((ext_vector_type(8)));

// ---------------------------------------------------------------- block reduce
__device__ __forceinline__ float block_reduce_sum(float v, float* sbuf) {
#pragma unroll
    for (int off = 32; off; off >>= 1) v += __shfl_down(v, off);
    __syncthreads();
    int wave = threadIdx.x >> 6;
    int lane = threadIdx.x & 63;
    if (lane == 0) sbuf[wave] = v;
    __syncthreads();
    return sbuf[0] + sbuf[1] + sbuf[2] + sbuf[3];
}

// ---------------------------------------------------------------- bf16 MFMA GEMM
// C[rows,N] = A[rows,Kd] @ Bt[N,Kd]^T. 128x128 tile, BK=64. Grouped row-panel swizzle.
template<int OUT_BF16, int RELU>
__global__ __launch_bounds__(256, 2) void gemm_mfma(
    const bf16_t* __restrict__ A, const bf16_t* __restrict__ Bt,
    const float* __restrict__ bias, void* __restrict__ C,
    int Kd, int N, int nx, int ny)
{
    __shared__ bf16_t As[128 * 64];
    __shared__ bf16_t Bs[128 * 64];
    const int tid = threadIdx.x;
    const int w = tid >> 6, l = tid & 63;
    // block swizzle: panels of 8 row-tiles, serpentine over columns
    int per = 8 * nx;
    int g = blockIdx.x / per, rr = blockIdx.x % per;
    int gs = ny - g * 8; if (gs > 8) gs = 8;
    const int row0 = (g * 8 + rr % gs) * 128, col0 = (rr / gs) * 128;

    const int srow = w * 8 + (l >> 3);
    const int gchunk = (l & 7) ^ ((l >> 3) & 7);
    const bf16_t* gA = A + (size_t)(row0 + srow) * Kd + gchunk * 8;
    const bf16_t* gB = Bt + (size_t)(col0 + srow) * Kd + gchunk * 8;

    const int wm = w >> 1, wn = w & 1;
    f32x4 acc[4][4] = {};

    for (int k0 = 0; k0 < Kd; k0 += 64) {
#pragma unroll
        for (int c = 0; c < 4; ++c) {
            __builtin_amdgcn_global_load_lds(
                (const __attribute__((address_space(1))) void*)(gA + (size_t)(c * 32) * Kd + k0),
                (__attribute__((address_space(3))) void*)(As + (c * 256 + w * 64) * 8), 16, 0, 0);
            __builtin_amdgcn_global_load_lds(
                (const __attribute__((address_space(1))) void*)(gB + (size_t)(c * 32) * Kd + k0),
                (__attribute__((address_space(3))) void*)(Bs + (c * 256 + w * 64) * 8), 16, 0, 0);
        }
        __syncthreads();
#pragma unroll
        for (int ks = 0; ks < 2; ++ks) {
            bf16x8 af[4], bfr[4];
#pragma unroll
            for (int i = 0; i < 4; ++i) {
                int arow = wm * 64 + i * 16 + (l & 15);
                int slot = (ks * 4 + (l >> 4)) ^ (l & 7);
                af[i] = *(const bf16x8*)(As + arow * 64 + slot * 8);
                int brow = wn * 64 + i * 16 + (l & 15);
                bfr[i] = *(const bf16x8*)(Bs + brow * 64 + slot * 8);
            }
#pragma unroll
            for (int i = 0; i < 4; ++i)
#pragma unroll
                for (int j = 0; j < 4; ++j)
                    acc[i][j] = __builtin_amdgcn_mfma_f32_16x16x32_bf16(af[i], bfr[j], acc[i][j], 0, 0, 0);
        }
        __syncthreads();
    }

#pragma unroll
    for (int i = 0; i < 4; ++i) {
        int row = row0 + wm * 64 + i * 16 + (l >> 4) * 4;
#pragma unroll
        for (int j = 0; j < 4; ++j) {
            int col = col0 + wn * 64 + j * 16 + (l & 15);
            float bv = bias ? bias[col] : 0.f;
#pragma unroll
            for (int r = 0; r < 4; ++r) {
                float v = acc[i][j][r] + bv;
                if (RELU) v = fmaxf(v, 0.f);
                if (OUT_BF16) ((bf16_t*)C)[(size_t)(row + r) * N + col] = (bf16_t)v;
                else          ((float*)C)[(size_t)(row + r) * N + col] = v;
            }
        }
    }
}

static inline void launch_gemm(const bf16_t* A, const bf16_t* Bt, const float* bias, void* C,
                               int rows, int Kd, int N, bool relu, bool outbf, hipStream_t st) {
    int nx = N / 128, ny = rows / 128;
    dim3 grid(nx * ny);
    if (outbf) {
        if (relu) gemm_mfma<1, 1><<<grid, 256, 0, st>>>(A, Bt, bias, C, Kd, N, nx, ny);
        else      gemm_mfma<1, 0><<<grid, 256, 0, st>>>(A, Bt, bias, C, Kd, N, nx, ny);
    } else {
        if (relu) gemm_mfma<0, 1><<<grid, 256, 0, st>>>(A, Bt, bias, C, Kd, N, nx, ny);
        else      gemm_mfma<0, 0><<<grid, 256, 0, st>>>(A, Bt, bias, C, Kd, N, nx, ny);
    }
}

// ---------------------------------------------------------------- fp8 MX-MFMA GEMM
// C[rows,N] = A[rows,Kd] @ Bt[N,Kd]^T, fp8 e4m3 inputs, unit scales.
// 128x128 tile, BK=128 (2 k-steps of mfma_scale 32x32x64 per stage).
// LDS layout (16B chunks): idx(row,c) = (row>>3)*64 + c*8 + (row&7), c in [0,8).
template<int OUT_FP8, int RELU>
__global__ __launch_bounds__(256, 2) void gemm_fp8(
    const unsigned char* __restrict__ A, const unsigned char* __restrict__ Bt,
    const float* __restrict__ bias, void* __restrict__ C,
    int Kd, int N, int nx, int ny)
{
    __shared__ unsigned char As[128 * 128];
    __shared__ unsigned char Bs[128 * 128];
    const int tid = threadIdx.x;
    const int w = tid >> 6, l = tid & 63;
    int per = 8 * nx;
    int g = blockIdx.x / per, rrb = blockIdx.x % per;
    int gs = ny - g * 8; if (gs > 8) gs = 8;
    const int row0 = (g * 8 + rrb % gs) * 128, col0 = (rrb / gs) * 128;
    const int wm = w >> 1, wn = w & 1;
    const int SA = 0x7F7F7F7F;          // E8M0 scale = 1.0 in every byte

    // staging source mapping: idx = q*256 + tid; row=(idx>>6)*8+(idx&7), c=(idx>>3)&7
    int sidx = tid;
    int srow = ((sidx >> 6) << 3) + (sidx & 7);
    int sc   = (sidx >> 3) & 7;
    const unsigned char* gA = A + (size_t)(row0 + srow) * Kd + sc * 16;
    const unsigned char* gB = Bt + (size_t)(col0 + srow) * Kd + sc * 16;

    f32x16 acc[2][2] = {};

    for (int k0 = 0; k0 < Kd; k0 += 128) {
#pragma unroll
        for (int q = 0; q < 4; ++q) {
            // idx advances by 256 per q: row advances by 32 ( (idx>>6) += 4 ), c unchanged
            __builtin_amdgcn_global_load_lds(
                (const __attribute__((address_space(1))) void*)(gA + (size_t)(q * 32) * Kd + k0),
                (__attribute__((address_space(3))) void*)(As + (q * 256 + w * 64) * 16), 16, 0, 0);
            __builtin_amdgcn_global_load_lds(
                (const __attribute__((address_space(1))) void*)(gB + (size_t)(q * 32) * Kd + k0),
                (__attribute__((address_space(3))) void*)(Bs + (q * 256 + w * 64) * 16), 16, 0, 0);
        }
        __syncthreads();
#pragma unroll
        for (int s = 0; s < 2; ++s) {
            i32x8 af[2], bfr[2];
            int cbase = s * 4 + ((l >> 5) << 1);
#pragma unroll
            for (int i = 0; i < 2; ++i) {
                int row = wm * 64 + i * 32 + (l & 31);
                int idx0 = ((row >> 3) << 6) + cbase * 8 + (row & 7);
                i32x4 lo = *(const i32x4*)(As + idx0 * 16);
                i32x4 hi = *(const i32x4*)(As + (idx0 + 8) * 16);
                i32x8 a;
                a[0] = lo[0]; a[1] = lo[1]; a[2] = lo[2]; a[3] = lo[3];
                a[4] = hi[0]; a[5] = hi[1]; a[6] = hi[2]; a[7] = hi[3];
                af[i] = a;
                int colr = wn * 64 + i * 32 + (l & 31);
                int jdx0 = ((colr >> 3) << 6) + cbase * 8 + (colr & 7);
                lo = *(const i32x4*)(Bs + jdx0 * 16);
                hi = *(const i32x4*)(Bs + (jdx0 + 8) * 16);
                i32x8 b;
                b[0] = lo[0]; b[1] = lo[1]; b[2] = lo[2]; b[3] = lo[3];
                b[4] = hi[0]; b[5] = hi[1]; b[6] = hi[2]; b[7] = hi[3];
                bfr[i] = b;
            }
#pragma unroll
            for (int i = 0; i < 2; ++i)
#pragma unroll
                for (int j = 0; j < 2; ++j)
                    acc[i][j] = __builtin_amdgcn_mfma_scale_f32_32x32x64_f8f6f4(
                        af[i], bfr[j], acc[i][j], 0, 0, 0, SA, 0, SA);
        }
        __syncthreads();
    }

    // epilogue: 32x32 C/D layout col=lane&31, row=(reg&3)+8*(reg>>2)+4*(lane>>5)
#pragma unroll
    for (int i = 0; i < 2; ++i) {
        int rbase = row0 + wm * 64 + i * 32 + 4 * (l >> 5);
#pragma unroll
        for (int j = 0; j < 2; ++j) {
            int col = col0 + wn * 64 + j * 32 + (l & 31);
            float bv = bias ? bias[col] : 0.f;
#pragma unroll
            for (int reg = 0; reg < 16; ++reg) {
                int row = rbase + (reg & 3) + 8 * (reg >> 2);
                float v = acc[i][j][reg] + bv;
                if (RELU) v = fmaxf(v, 0.f);
                if (OUT_FP8)
                    ((unsigned char*)C)[(size_t)row * N + col] =
                        (unsigned char)(__builtin_amdgcn_cvt_pk_fp8_f32(v, v, 0, false) & 0xff);
                else
                    ((float*)C)[(size_t)row * N + col] = v;
            }
        }
    }
}

static inline void launch_fp8(const unsigned char* A, const unsigned char* Bt, const float* bias,
                              void* C, int rows, int Kd, int N, bool relu, bool outfp8, hipStream_t st) {
    int nx = N / 128, ny = rows / 128;
    dim3 grid(nx * ny);
    if (outfp8) {
        if (relu) gemm_fp8<1, 1><<<grid, 256, 0, st>>>(A, Bt, bias, C, Kd, N, nx, ny);
        else      gemm_fp8<1, 0><<<grid, 256, 0, st>>>(A, Bt, bias, C, Kd, N, nx, ny);
    } else {
        if (relu) gemm_fp8<0, 1><<<grid, 256, 0, st>>>(A, Bt, bias, C, Kd, N, nx, ny);
        else      gemm_fp8<0, 0><<<grid, 256, 0, st>>>(A, Bt, bias, C, Kd, N, nx, ny);
    }
}

// ---------------------------------------------------------------- transpose fp32 W[Kd][N] -> bf16 Wt[N][Kd]
__global__ __launch_bounds__(256) void transpose_bf16(
    const float* __restrict__ W, bf16_t* __restrict__ Wt, int Kd, int N)
{
    __shared__ float t[32][33];
    int bx = blockIdx.x * 32, by = blockIdx.y * 32;
    int x = threadIdx.x & 31, y = threadIdx.x >> 5;
#pragma unroll
    for (int yy = y; yy < 32; yy += 8) t[yy][x] = W[(size_t)(by + yy) * N + bx + x];
    __syncthreads();
#pragma unroll
    for (int yy = y; yy < 32; yy += 8) Wt[(size_t)(bx + yy) * Kd + by + x] = (bf16_t)t[x][yy];
}

// ---------------------------------------------------------------- transpose fp32 W[Kd][N] -> fp8 Wt[N][Kd]
__global__ __launch_bounds__(256) void transpose_fp8(
    const float* __restrict__ W, unsigned char* __restrict__ Wt, int Kd, int N)
{
    __shared__ float t[32][33];
    int bx = blockIdx.x * 32, by = blockIdx.y * 32;
    int x = threadIdx.x & 31, y = threadIdx.x >> 5;
#pragma unroll
    for (int yy = y; yy < 32; yy += 8) t[yy][x] = W[(size_t)(by + yy) * N + bx + x];
    __syncthreads();
    int xg = threadIdx.x & 7, yo = threadIdx.x >> 3;   // yo: out-row 0..31, xg: 4-col group
    int lo = __builtin_amdgcn_cvt_pk_fp8_f32(t[xg * 4 + 0][yo], t[xg * 4 + 1][yo], 0, false);
    int both = __builtin_amdgcn_cvt_pk_fp8_f32(t[xg * 4 + 2][yo], t[xg * 4 + 3][yo], lo, true);
    *(int*)(Wt + (size_t)(bx + yo) * Kd + by + xg * 4) = both;
}

// ---------------------------------------------------------------- fp32 -> bf16
__global__ __launch_bounds__(256) void cvt_bf16(
    const float* __restrict__ x, bf16_t* __restrict__ y, int n4)
{
    int i = blockIdx.x * 256 + threadIdx.x;
    if (i < n4) {
        float4 v = ((const float4*)x)[i];
        bf16_t o4[4] = {(bf16_t)v.x, (bf16_t)v.y, (bf16_t)v.z, (bf16_t)v.w};
        ((uint2*)y)[i] = *(uint2*)o4;
    }
}

// ---------------------------------------------------------------- bias pack [bq|bk|bv|0|0] (3840)
__global__ __launch_bounds__(256) void pack_bias5(
    const float* __restrict__ bq, const float* __restrict__ bk,
    const float* __restrict__ bv, float* __restrict__ o)
{
    int i = blockIdx.x * 256 + threadIdx.x;
    if (i >= 3840) return;
    float v = 0.f;
    if (i < 768) v = bq[i];
    else if (i < 1536) v = bk[i - 768];
    else if (i < 2304) v = bv[i - 1536];
    o[i] = v;
}

// ---------------------------------------------------------------- span means
__global__ __launch_bounds__(256) void spans_kernel(
    const float* __restrict__ txt, const int* __restrict__ starts,
    const int* __restrict__ lens, float* __restrict__ mention,
    bf16_t* __restrict__ mentionb, bf16_t* __restrict__ ctxb)
{
    int m = blockIdx.x;
    int st = starts[m], ln = lens[m];
    int en = st + ln;
    int cs = st - CTX_W; if (cs < 0) cs = 0;
    int ce = en + CTX_W; if (ce > S_LEN - 1) ce = S_LEN - 1;
    int c = threadIdx.x;
    float s0 = 0.f, s1 = 0.f, s2 = 0.f;
    for (int r = st; r <= en; ++r) {
        const float* tr = txt + (size_t)r * D_DIM;
        s0 += tr[c]; s1 += tr[c + 256]; s2 += tr[c + 512];
    }
    float inv = 1.f / (float)(ln + 1);
    float* mp = mention + (size_t)m * D_DIM;
    bf16_t* mb = mentionb + (size_t)m * D_DIM;
    mp[c] = s0 * inv; mp[c + 256] = s1 * inv; mp[c + 512] = s2 * inv;
    mb[c] = (bf16_t)(s0 * inv); mb[c + 256] = (bf16_t)(s1 * inv); mb[c + 512] = (bf16_t)(s2 * inv);

    s0 = 0.f; s1 = 0.f; s2 = 0.f;
    for (int r = cs; r < ce; ++r) {
        const float* tr = txt + (size_t)r * D_DIM;
        s0 += tr[c]; s1 += tr[c + 256]; s2 += tr[c + 512];
    }
    inv = 1.f / (float)(ce - cs);
    bf16_t* cp = ctxb + (size_t)m * D_DIM;
    cp[c] = (bf16_t)(s0 * inv); cp[c + 256] = (bf16_t)(s1 * inv); cp[c + 512] = (bf16_t)(s2 * inv);
}

// ---------------------------------------------------------------- uni_w2 column-mean
__global__ __launch_bounds__(256) void w2bar_kernel(
    const float* __restrict__ uni_w2, const float* __restrict__ uni_b2,
    float* __restrict__ w2bar, float* __restrict__ b2bar)
{
    __shared__ float sbuf[4];
    int d = blockIdx.x;
    float s = 0.f;
    if (d < D_DIM) {
        for (int j = threadIdx.x; j < D_DIM; j += 256) s += uni_w2[(size_t)d * D_DIM + j];
        s = block_reduce_sum(s, sbuf);
        if (threadIdx.x == 0) w2bar[d] = s * (1.f / (float)D_DIM);
    } else {
        for (int j = threadIdx.x; j < D_DIM; j += 256) s += uni_b2[j];
        s = block_reduce_sum(s, sbuf);
        if (threadIdx.x == 0) *b2bar = s * (1.f / (float)D_DIM);
    }
}

// ---------------------------------------------------------------- 2x2 attention (packed stride 3840)
__global__ __launch_bounds__(512) void attn_kernel(
    const bf16_t* __restrict__ qkvm, const bf16_t* __restrict__ qkvc,
    bf16_t* __restrict__ o, int g0)
{
    int lc = blockIdx.x;
    int gg = g0 + lc;
    int m = gg >> 5;
    int h = threadIdx.x >> 6;
    int lane = threadIdx.x & 63;
    const bf16_t* bm = qkvm + (size_t)m * 3840 + h * DH_DIM;
    const bf16_t* bc = qkvc + (size_t)lc * 3840 + h * DH_DIM;

    float s00 = 0.f, s01 = 0.f, s10 = 0.f, s11 = 0.f;
    for (int d = lane; d < DH_DIM; d += 64) {
        float qmv = (float)bm[d], kmv = (float)bm[d + 768];
        float qcv = (float)bc[d], kcv = (float)bc[d + 768];
        s00 += qmv * kmv; s01 += qmv * kcv; s10 += qcv * kmv; s11 += qcv * kcv;
    }
#pragma unroll
    for (int off = 32; off; off >>= 1) {
        s00 += __shfl_down(s00, off); s01 += __shfl_down(s01, off);
        s10 += __shfl_down(s10, off); s11 += __shfl_down(s11, off);
    }
    s00 = __shfl(s00, 0); s01 = __shfl(s01, 0);
    s10 = __shfl(s10, 0); s11 = __shfl(s11, 0);
    const float sc = 0.1020620726159658f;  // 1/sqrt(96)
    s00 *= sc; s01 *= sc; s10 *= sc; s11 *= sc;
    float m0 = fmaxf(s00, s01), m1 = fmaxf(s10, s11);
    float e00 = expf(s00 - m0), e01 = expf(s01 - m0);
    float e10 = expf(s10 - m1), e11 = expf(s11 - m1);
    float i0 = 1.f / (e00 + e01), i1 = 1.f / (e10 + e11);
    float a00 = e00 * i0, a01 = e01 * i0, a10 = e10 * i1, a11 = e11 * i1;

    bf16_t* o0 = o + ((size_t)lc * 2) * D_DIM + h * DH_DIM;
    bf16_t* o1 = o0 + D_DIM;
    for (int d = lane; d < DH_DIM; d += 64) {
        float vmv = (float)bm[d + 1536], vcv = (float)bc[d + 1536];
        o0[d] = (bf16_t)(a00 * vmv + a01 * vcv);
        o1[d] = (bf16_t)(a10 * vmv + a11 * vcv);
    }
}

// ---------------------------------------------------------------- LN1: x1 = LN(x + pre) in place (fp32) + fp8 copy
__global__ __launch_bounds__(256) void ln1_kernel(
    float* __restrict__ x1f, const float* __restrict__ mention,
    const float* __restrict__ cand, const float* __restrict__ g,
    const float* __restrict__ b, unsigned char* __restrict__ x1q, int g0)
{
    __shared__ float sbuf[4];
    int r = blockIdx.x;
    int lc = r >> 1, pos = r & 1;
    int gg = g0 + lc, m = gg >> 5;
    const float* xr = pos ? (cand + (size_t)gg * D_DIM) : (mention + (size_t)m * D_DIM);
    float* pr = x1f + (size_t)r * D_DIM;
    int c = threadIdx.x;
    float v0 = xr[c] + pr[c];
    float v1 = xr[c + 256] + pr[c + 256];
    float v2 = xr[c + 512] + pr[c + 512];
    float mu = block_reduce_sum(v0 + v1 + v2, sbuf) * (1.f / (float)D_DIM);
    float d0 = v0 - mu, d1 = v1 - mu, d2 = v2 - mu;
    float var = block_reduce_sum(d0 * d0 + d1 * d1 + d2 * d2, sbuf) * (1.f / (float)D_DIM);
    float inv = rsqrtf(var + 1e-5f);
    float o0 = d0 * inv * g[c] + b[c];
    float o1 = d1 * inv * g[c + 256] + b[c + 256];
    float o2 = d2 * inv * g[c + 512] + b[c + 512];
    pr[c] = o0; pr[c + 256] = o1; pr[c + 512] = o2;
    unsigned char* qp = x1q + (size_t)r * D_DIM;
    qp[c] = (unsigned char)(__builtin_amdgcn_cvt_pk_fp8_f32(o0, o0, 0, false) & 0xff);
    qp[c + 256] = (unsigned char)(__builtin_amdgcn_cvt_pk_fp8_f32(o1, o1, 0, false) & 0xff);
    qp[c + 512] = (unsigned char)(__builtin_amdgcn_cvt_pk_fp8_f32(o2, o2, 0, false) & 0xff);
}

// ---------------------------------------------------------------- fused heads: LN2 + atg + relik + uni
__global__ __launch_bounds__(256) void heads_kernel(
    const float* __restrict__ x1f, const float* __restrict__ x2f,
    const float* __restrict__ g2, const float* __restrict__ b2g,
    const float* __restrict__ Ar, const float* __restrict__ Au,
    const bf16_t* __restrict__ qkvc, const float* __restrict__ rw2,
    const float* __restrict__ rb2, const float* __restrict__ w2bar,
    const float* __restrict__ b2bar, float* __restrict__ out, int g0)
{
    __shared__ float sbuf[4];
    int lc = blockIdx.x;
    int gg = g0 + lc, m = gg >> 5;
    int c = threadIdx.x;
    float e[2][3];
#pragma unroll
    for (int rr = 0; rr < 2; ++rr) {
        const float* x1 = x1f + (size_t)(2 * lc + rr) * D_DIM;
        const float* x2 = x2f + (size_t)(2 * lc + rr) * D_DIM;
        float v0 = x1[c] + x2[c];
        float v1 = x1[c + 256] + x2[c + 256];
        float v2 = x1[c + 512] + x2[c + 512];
        float mu = block_reduce_sum(v0 + v1 + v2, sbuf) * (1.f / (float)D_DIM);
        float d0 = v0 - mu, d1 = v1 - mu, d2 = v2 - mu;
        float var = block_reduce_sum(d0 * d0 + d1 * d1 + d2 * d2, sbuf) * (1.f / (float)D_DIM);
        float inv = rsqrtf(var + 1e-5f);
        e[rr][0] = d0 * inv * g2[c] + b2g[c];
        e[rr][1] = d1 * inv * g2[c + 256] + b2g[c + 256];
        e[rr][2] = d2 * inv * g2[c + 512] + b2g[c + 512];
    }
    // atg
    float dd = e[0][0] * e[1][0] + e[0][1] * e[1][1] + e[0][2] * e[1][2];
    float aa = e[0][0] * e[0][0] + e[0][1] * e[0][1] + e[0][2] * e[0][2];
    float bb = e[1][0] * e[1][0] + e[1][1] * e[1][1] + e[1][2] * e[1][2];
    dd = block_reduce_sum(dd, sbuf);
    aa = block_reduce_sum(aa, sbuf);
    bb = block_reduce_sum(bb, sbuf);
    // relik
    const float* ar = Ar + (size_t)m * D_DIM;
    const bf16_t* br = qkvc + (size_t)lc * 3840 + 2304;
    float rs = fmaxf(ar[c] + (float)br[c], 0.f) * rw2[c]
             + fmaxf(ar[c + 256] + (float)br[c + 256], 0.f) * rw2[c + 256]
             + fmaxf(ar[c + 512] + (float)br[c + 512], 0.f) * rw2[c + 512];
    rs = block_reduce_sum(rs, sbuf);
    // uni
    const float* au = Au + (size_t)m * D_DIM;
    const bf16_t* bu = qkvc + (size_t)lc * 3840 + 3072;
    float us = fmaxf(au[c] + (float)bu[c], 0.f) * w2bar[c]
             + fmaxf(au[c + 256] + (float)bu[c + 256], 0.f) * w2bar[c + 256]
             + fmaxf(au[c + 512] + (float)bu[c + 512], 0.f) * w2bar[c + 512];
    us = block_reduce_sum(us, sbuf);
    if (threadIdx.x == 0) {
        float n0 = fmaxf(sqrtf(aa), 1e-8f);
        float n1 = fmaxf(sqrtf(bb), 1e-8f);
        out[MK_CNT + gg] = dd / (n0 * n1);
        out[gg] = rs + rb2[0];
        float z = us + *b2bar;
        out[2 * MK_CNT + gg] = 1.f / (1.f + expf(-z));
    }
}

// ---------------------------------------------------------------- host
extern "C" void kernel_launch(void* const* d_in, const int* in_sizes, int n_in,
                              void* d_out, int out_size, void* d_ws, size_t ws_size,
                              hipStream_t stream) {
    const float* text     = (const float*)d_in[0];
    const float* cand     = (const float*)d_in[1];
    const int*   starts   = (const int*)d_in[2];
    const int*   lens     = (const int*)d_in[3];
    const float* relik_w1 = (const float*)d_in[4];
    const float* relik_b1 = (const float*)d_in[5];
    const float* relik_w2 = (const float*)d_in[6];
    const float* relik_b2 = (const float*)d_in[7];
    const float* wq = (const float*)d_in[8];
    const float* bq = (const float*)d_in[9];
    const float* wk = (const float*)d_in[10];
    const float* bk = (const float*)d_in[11];
    const float* wv = (const float*)d_in[12];
    const float* bv = (const float*)d_in[13];
    const float* wo = (const float*)d_in[14];
    const float* bo = (const float*)d_in[15];
    const float* ln1_g = (const float*)d_in[16];
    const float* ln1_b = (const float*)d_in[17];
    const float* ffn_w1 = (const float*)d_in[18];
    const float* ffn_b1 = (const float*)d_in[19];
    const float* ffn_w2 = (const float*)d_in[20];
    const float* ffn_b2 = (const float*)d_in[21];
    const float* ln2_g = (const float*)d_in[22];
    const float* ln2_b = (const float*)d_in[23];
    const float* uni_w1 = (const float*)d_in[24];
    const float* uni_b1 = (const float*)d_in[25];
    const float* uni_w2 = (const float*)d_in[26];
    const float* uni_b2 = (const float*)d_in[27];
    float* out = (float*)d_out;

    const size_t MD = (size_t)M_CNT * D_DIM;
    const size_t DD = (size_t)D_DIM * D_DIM;

    // fixed ~21.25M floats; per chunk 7680*NC floats
    size_t fixed_f = 21300000;
    int NC = 16384;
    while (NC > 128 && (fixed_f + (size_t)NC * 7680) * 4 > ws_size) NC >>= 1;
    const size_t NCD = (size_t)NC * D_DIM;

    float* p = (float*)d_ws;
    float* mention = p; p += MD;
    float* Ar      = p; p += MD;
    float* Au      = p; p += MD;
    float* bqkv5   = p; p += 3840;
    float* w2bar   = p; p += 768;
    float* b2bar   = p; p += 64;
    bf16_t* mentionb = (bf16_t*)p; p += MD / 2;
    bf16_t* ctxb     = (bf16_t*)p; p += MD / 2;
    bf16_t* qkvm     = (bf16_t*)p; p += (size_t)M_CNT * 3840 / 2;
    bf16_t* wcandT   = (bf16_t*)p; p += (size_t)3840 * 768 / 2;
    bf16_t* woT      = (bf16_t*)p; p += DD / 2;
    bf16_t* relikAT  = (bf16_t*)p; p += DD / 2;
    bf16_t* uniAT    = (bf16_t*)p; p += DD / 2;
    unsigned char* w1q = (unsigned char*)p; p += (size_t)3072 * 768 / 4;
    unsigned char* w2q = (unsigned char*)p; p += (size_t)3072 * 768 / 4;
    bf16_t* candb    = (bf16_t*)p; p += (size_t)MK_CNT * D_DIM / 2;
    // per-chunk
    bf16_t* qkvcb = (bf16_t*)p; p += (size_t)NC * 3840 / 2;
    bf16_t* obuf  = (bf16_t*)p; p += 2 * NCD / 2;
    float*  x1f   = p; p += 2 * NCD;
    float*  x2f   = p; p += 2 * NCD;
    unsigned char* x1q = (unsigned char*)p; p += 2 * NCD / 4;
    unsigned char* hb  = (unsigned char*)p; p += (size_t)2 * NC * 3072 / 4;

    // ---- weight prep ----
    dim3 t768(768 / 32, 768 / 32);
    transpose_bf16<<<t768, 256, 0, stream>>>(wq, wcandT, 768, 768);
    transpose_bf16<<<t768, 256, 0, stream>>>(wk, wcandT + DD, 768, 768);
    transpose_bf16<<<t768, 256, 0, stream>>>(wv, wcandT + 2 * DD, 768, 768);
    transpose_bf16<<<t768, 256, 0, stream>>>(relik_w1 + DD, wcandT + 3 * DD, 768, 768);
    transpose_bf16<<<t768, 256, 0, stream>>>(uni_w1 + DD, wcandT + 4 * DD, 768, 768);
    transpose_bf16<<<t768, 256, 0, stream>>>(wo, woT, 768, 768);
    transpose_bf16<<<t768, 256, 0, stream>>>(relik_w1, relikAT, 768, 768);
    transpose_bf16<<<t768, 256, 0, stream>>>(uni_w1, uniAT, 768, 768);
    transpose_fp8<<<dim3(3072 / 32, 768 / 32), 256, 0, stream>>>(ffn_w1, w1q, 768, 3072);
    transpose_fp8<<<dim3(768 / 32, 3072 / 32), 256, 0, stream>>>(ffn_w2, w2q, 3072, 768);
    pack_bias5<<<15, 256, 0, stream>>>(bq, bk, bv, bqkv5);
    w2bar_kernel<<<D_DIM + 1, 256, 0, stream>>>(uni_w2, uni_b2, w2bar, b2bar);
    cvt_bf16<<<(MK_CNT * D_DIM / 4 + 255) / 256, 256, 0, stream>>>(cand, candb, MK_CNT * D_DIM / 4);

    // ---- per-mention precompute ----
    spans_kernel<<<M_CNT, 256, 0, stream>>>(text, starts, lens, mention, mentionb, ctxb);
    launch_gemm(mentionb, wcandT, bqkv5, qkvm, M_CNT, 768, 3840, false, true, stream);
    launch_gemm(mentionb, relikAT, relik_b1, Ar, M_CNT, 768, 768, false, false, stream);
    launch_gemm(ctxb, uniAT, uni_b1, Au, M_CNT, 768, 768, false, false, stream);

    int nch = MK_CNT / NC;
    for (int c = 0; c < nch; ++c) {
        int g0 = c * NC;
        const bf16_t* cc = candb + (size_t)g0 * D_DIM;
        launch_gemm(cc, wcandT, bqkv5, qkvcb, NC, 768, 3840, false, true, stream);

        attn_kernel<<<NC, 512, 0, stream>>>(qkvm, qkvcb, obuf, g0);

        launch_gemm(obuf, woT, bo, x1f, 2 * NC, 768, 768, false, false, stream);
        ln1_kernel<<<2 * NC, 256, 0, stream>>>(x1f, mention, cand, ln1_g, ln1_b, x1q, g0);

        launch_fp8(x1q, w1q, ffn_b1, hb, 2 * NC, 768, 3072, true, true, stream);
        launch_fp8(hb, w2q, ffn_b2, x2f, 2 * NC, 3072, 768, false, false, stream);

        heads_kernel<<<NC, 256, 0, stream>>>(x1f, x2f, ln2_g, ln2_b, Ar, Au, qkvcb,
                                             relik_w2, relik_b2, w2bar, b2bar, out, g0);
    }
}

// Round 5
// 1329.729 us; speedup vs baseline: 9.8854x; 1.2867x over previous
//
#include <hip/hip_runtime.h>
#include <math.h>

#define S_LEN 4096
#define D_DIM 768
#define M_CNT 1024
#define K_CNT 32
#define MK_CNT 32768
#define DH_DIM 96
#define CTX_W 10

typedef __bf16 bf16_t;
typedef bf16_t bf16x8 __attribute__((ext_vector_type(8)));
typedef float f32x4 __attribute__((ext_vector_type(4)));
typedef float f32x16 __attribute__((ext_vector_type(16)));
typedef int i32x4 __attribute__((ext_vector_type(4)));
typedef int i32x8 __attribute__((ext_vector_type(8)));

// ---------------------------------------------------------------- block reduce
__device__ __forceinline__ float block_reduce_sum(float v, float* sbuf) {
#pragma unroll
    for (int off = 32; off; off >>= 1) v += __shfl_down(v, off);
    __syncthreads();
    int wave = threadIdx.x >> 6;
    int lane = threadIdx.x & 63;
    if (lane == 0) sbuf[wave] = v;
    __syncthreads();
    return sbuf[0] + sbuf[1] + sbuf[2] + sbuf[3];
}

// ---------------------------------------------------------------- bf16 MFMA GEMM
// C[rows,N] = A[rows,Kd] @ Bt[N,Kd]^T. 128x128 tile, BK=64. Grouped row-panel swizzle.
template<int OUT_BF16, int RELU>
__global__ __launch_bounds__(256, 2) void gemm_mfma(
    const bf16_t* __restrict__ A, const bf16_t* __restrict__ Bt,
    const float* __restrict__ bias, void* __restrict__ C,
    int Kd, int N, int nx, int ny)
{
    __shared__ bf16_t As[128 * 64];
    __shared__ bf16_t Bs[128 * 64];
    const int tid = threadIdx.x;
    const int w = tid >> 6, l = tid & 63;
    int per = 8 * nx;
    int g = blockIdx.x / per, rr = blockIdx.x % per;
    int gs = ny - g * 8; if (gs > 8) gs = 8;
    const int row0 = (g * 8 + rr % gs) * 128, col0 = (rr / gs) * 128;

    const int srow = w * 8 + (l >> 3);
    const int gchunk = (l & 7) ^ ((l >> 3) & 7);
    const bf16_t* gA = A + (size_t)(row0 + srow) * Kd + gchunk * 8;
    const bf16_t* gB = Bt + (size_t)(col0 + srow) * Kd + gchunk * 8;

    const int wm = w >> 1, wn = w & 1;
    f32x4 acc[4][4] = {};

    for (int k0 = 0; k0 < Kd; k0 += 64) {
#pragma unroll
        for (int c = 0; c < 4; ++c) {
            __builtin_amdgcn_global_load_lds(
                (const __attribute__((address_space(1))) void*)(gA + (size_t)(c * 32) * Kd + k0),
                (__attribute__((address_space(3))) void*)(As + (c * 256 + w * 64) * 8), 16, 0, 0);
            __builtin_amdgcn_global_load_lds(
                (const __attribute__((address_space(1))) void*)(gB + (size_t)(c * 32) * Kd + k0),
                (__attribute__((address_space(3))) void*)(Bs + (c * 256 + w * 64) * 8), 16, 0, 0);
        }
        __syncthreads();
#pragma unroll
        for (int ks = 0; ks < 2; ++ks) {
            bf16x8 af[4], bfr[4];
#pragma unroll
            for (int i = 0; i < 4; ++i) {
                int arow = wm * 64 + i * 16 + (l & 15);
                int slot = (ks * 4 + (l >> 4)) ^ (l & 7);
                af[i] = *(const bf16x8*)(As + arow * 64 + slot * 8);
                int brow = wn * 64 + i * 16 + (l & 15);
                bfr[i] = *(const bf16x8*)(Bs + brow * 64 + slot * 8);
            }
#pragma unroll
            for (int i = 0; i < 4; ++i)
#pragma unroll
                for (int j = 0; j < 4; ++j)
                    acc[i][j] = __builtin_amdgcn_mfma_f32_16x16x32_bf16(af[i], bfr[j], acc[i][j], 0, 0, 0);
        }
        __syncthreads();
    }

#pragma unroll
    for (int i = 0; i < 4; ++i) {
        int row = row0 + wm * 64 + i * 16 + (l >> 4) * 4;
#pragma unroll
        for (int j = 0; j < 4; ++j) {
            int col = col0 + wn * 64 + j * 16 + (l & 15);
            float bv = bias ? bias[col] : 0.f;
#pragma unroll
            for (int r = 0; r < 4; ++r) {
                float v = acc[i][j][r] + bv;
                if (RELU) v = fmaxf(v, 0.f);
                if (OUT_BF16) ((bf16_t*)C)[(size_t)(row + r) * N + col] = (bf16_t)v;
                else          ((float*)C)[(size_t)(row + r) * N + col] = v;
            }
        }
    }
}

static inline void launch_gemm(const bf16_t* A, const bf16_t* Bt, const float* bias, void* C,
                               int rows, int Kd, int N, bool relu, bool outbf, hipStream_t st) {
    int nx = N / 128, ny = rows / 128;
    dim3 grid(nx * ny);
    if (outbf) {
        if (relu) gemm_mfma<1, 1><<<grid, 256, 0, st>>>(A, Bt, bias, C, Kd, N, nx, ny);
        else      gemm_mfma<1, 0><<<grid, 256, 0, st>>>(A, Bt, bias, C, Kd, N, nx, ny);
    } else {
        if (relu) gemm_mfma<0, 1><<<grid, 256, 0, st>>>(A, Bt, bias, C, Kd, N, nx, ny);
        else      gemm_mfma<0, 0><<<grid, 256, 0, st>>>(A, Bt, bias, C, Kd, N, nx, ny);
    }
}

// ---------------------------------------------------------------- fp8 MX-MFMA GEMM
// C[rows,N] = A[rows,Kd] @ Bt[N,Kd]^T, fp8 e4m3, unit scales. 128x128 tile, BK=128.
// LDS: 16B chunk (row R, global chunk g) stored at slot R*8 + (g ^ (R&7))  -> bank-conflict-free.
// OMODE: 0=f32, 1=fp8, 2=bf16
template<int OMODE, int RELU>
__global__ __launch_bounds__(256, 2) void gemm_fp8(
    const unsigned char* __restrict__ A, const unsigned char* __restrict__ Bt,
    const float* __restrict__ bias, void* __restrict__ C,
    int Kd, int N, int nx, int ny)
{
    __shared__ unsigned char As[128 * 128];
    __shared__ unsigned char Bs[128 * 128];
    const int tid = threadIdx.x;
    const int w = tid >> 6, l = tid & 63;
    int per = 8 * nx;
    int g = blockIdx.x / per, rrb = blockIdx.x % per;
    int gs = ny - g * 8; if (gs > 8) gs = 8;
    const int row0 = (g * 8 + rrb % gs) * 128, col0 = (rrb / gs) * 128;
    const int wm = w >> 1, wn = w & 1;
    const int SA = 0x7F7F7F7F;          // E8M0 scale = 1.0 in every byte

    // staging: lane l -> row (q*32 + w*8 + (l>>3)), global chunk (l&7)^((l>>3)&7).
    // dest = wave-uniform base + lane*16 -> LDS slot R*8 + (l&7) = R*8 + g^(R&7).
    const int srow = w * 8 + (l >> 3);
    const int gch = (l & 7) ^ ((l >> 3) & 7);
    const unsigned char* gA = A + (size_t)(row0 + srow) * Kd + gch * 16;
    const unsigned char* gB = Bt + (size_t)(col0 + srow) * Kd + gch * 16;

    f32x16 acc[2][2] = {};

    for (int k0 = 0; k0 < Kd; k0 += 128) {
#pragma unroll
        for (int q = 0; q < 4; ++q) {
            __builtin_amdgcn_global_load_lds(
                (const __attribute__((address_space(1))) void*)(gA + (size_t)(q * 32) * Kd + k0),
                (__attribute__((address_space(3))) void*)(As + (q * 256 + w * 64) * 16), 16, 0, 0);
            __builtin_amdgcn_global_load_lds(
                (const __attribute__((address_space(1))) void*)(gB + (size_t)(q * 32) * Kd + k0),
                (__attribute__((address_space(3))) void*)(Bs + (q * 256 + w * 64) * 16), 16, 0, 0);
        }
        __syncthreads();
#pragma unroll
        for (int s = 0; s < 2; ++s) {
            i32x8 af[2], bfr[2];
            int cb = s * 4 + ((l >> 5) << 1);      // even base chunk for this k-half
#pragma unroll
            for (int i = 0; i < 2; ++i) {
                int row = wm * 64 + i * 32 + (l & 31);
                int sl0 = cb ^ (row & 7);
                int sl1 = (cb + 1) ^ (row & 7);
                i32x4 lo = *(const i32x4*)(As + (row * 8 + sl0) * 16);
                i32x4 hi = *(const i32x4*)(As + (row * 8 + sl1) * 16);
                i32x8 a;
                a[0] = lo[0]; a[1] = lo[1]; a[2] = lo[2]; a[3] = lo[3];
                a[4] = hi[0]; a[5] = hi[1]; a[6] = hi[2]; a[7] = hi[3];
                af[i] = a;
                int colr = wn * 64 + i * 32 + (l & 31);
                int tl0 = cb ^ (colr & 7);
                int tl1 = (cb + 1) ^ (colr & 7);
                lo = *(const i32x4*)(Bs + (colr * 8 + tl0) * 16);
                hi = *(const i32x4*)(Bs + (colr * 8 + tl1) * 16);
                i32x8 b;
                b[0] = lo[0]; b[1] = lo[1]; b[2] = lo[2]; b[3] = lo[3];
                b[4] = hi[0]; b[5] = hi[1]; b[6] = hi[2]; b[7] = hi[3];
                bfr[i] = b;
            }
#pragma unroll
            for (int i = 0; i < 2; ++i)
#pragma unroll
                for (int j = 0; j < 2; ++j)
                    acc[i][j] = __builtin_amdgcn_mfma_scale_f32_32x32x64_f8f6f4(
                        af[i], bfr[j], acc[i][j], 0, 0, 0, SA, 0, SA);
        }
        __syncthreads();
    }

    // 32x32 C/D layout: col=lane&31, row=(reg&3)+8*(reg>>2)+4*(lane>>5)
#pragma unroll
    for (int i = 0; i < 2; ++i) {
        int rbase = row0 + wm * 64 + i * 32 + 4 * (l >> 5);
#pragma unroll
        for (int j = 0; j < 2; ++j) {
            int col = col0 + wn * 64 + j * 32 + (l & 31);
            float bv = bias ? bias[col] : 0.f;
#pragma unroll
            for (int reg = 0; reg < 16; ++reg) {
                int row = rbase + (reg & 3) + 8 * (reg >> 2);
                float v = acc[i][j][reg] + bv;
                if (RELU) v = fmaxf(v, 0.f);
                if (OMODE == 1)
                    ((unsigned char*)C)[(size_t)row * N + col] =
                        (unsigned char)(__builtin_amdgcn_cvt_pk_fp8_f32(v, v, 0, false) & 0xff);
                else if (OMODE == 2)
                    ((bf16_t*)C)[(size_t)row * N + col] = (bf16_t)v;
                else
                    ((float*)C)[(size_t)row * N + col] = v;
            }
        }
    }
}

template<int OMODE, int RELU>
static inline void launch_fp8_t(const unsigned char* A, const unsigned char* Bt, const float* bias,
                                void* C, int rows, int Kd, int N, hipStream_t st) {
    int nx = N / 128, ny = rows / 128;
    gemm_fp8<OMODE, RELU><<<dim3(nx * ny), 256, 0, st>>>(A, Bt, bias, C, Kd, N, nx, ny);
}

// ---------------------------------------------------------------- transpose fp32 W[Kd][N] -> bf16 Wt[N][Kd]
__global__ __launch_bounds__(256) void transpose_bf16(
    const float* __restrict__ W, bf16_t* __restrict__ Wt, int Kd, int N)
{
    __shared__ float t[32][33];
    int bx = blockIdx.x * 32, by = blockIdx.y * 32;
    int x = threadIdx.x & 31, y = threadIdx.x >> 5;
#pragma unroll
    for (int yy = y; yy < 32; yy += 8) t[yy][x] = W[(size_t)(by + yy) * N + bx + x];
    __syncthreads();
#pragma unroll
    for (int yy = y; yy < 32; yy += 8) Wt[(size_t)(bx + yy) * Kd + by + x] = (bf16_t)t[x][yy];
}

// ---------------------------------------------------------------- transpose fp32 W[Kd][N] -> fp8 Wt[N][Kd]
__global__ __launch_bounds__(256) void transpose_fp8(
    const float* __restrict__ W, unsigned char* __restrict__ Wt, int Kd, int N)
{
    __shared__ float t[32][33];
    int bx = blockIdx.x * 32, by = blockIdx.y * 32;
    int x = threadIdx.x & 31, y = threadIdx.x >> 5;
#pragma unroll
    for (int yy = y; yy < 32; yy += 8) t[yy][x] = W[(size_t)(by + yy) * N + bx + x];
    __syncthreads();
    int xg = threadIdx.x & 7, yo = threadIdx.x >> 3;
    int lo = __builtin_amdgcn_cvt_pk_fp8_f32(t[xg * 4 + 0][yo], t[xg * 4 + 1][yo], 0, false);
    int both = __builtin_amdgcn_cvt_pk_fp8_f32(t[xg * 4 + 2][yo], t[xg * 4 + 3][yo], lo, true);
    *(int*)(Wt + (size_t)(bx + yo) * Kd + by + xg * 4) = both;
}

// ---------------------------------------------------------------- fp32 -> bf16
__global__ __launch_bounds__(256) void cvt_bf16(
    const float* __restrict__ x, bf16_t* __restrict__ y, int n4)
{
    int i = blockIdx.x * 256 + threadIdx.x;
    if (i < n4) {
        float4 v = ((const float4*)x)[i];
        bf16_t o4[4] = {(bf16_t)v.x, (bf16_t)v.y, (bf16_t)v.z, (bf16_t)v.w};
        ((uint2*)y)[i] = *(uint2*)o4;
    }
}

// ---------------------------------------------------------------- bias pack [bq|bk|bv|0|0] (3840)
__global__ __launch_bounds__(256) void pack_bias5(
    const float* __restrict__ bq, const float* __restrict__ bk,
    const float* __restrict__ bv, float* __restrict__ o)
{
    int i = blockIdx.x * 256 + threadIdx.x;
    if (i >= 3840) return;
    float v = 0.f;
    if (i < 768) v = bq[i];
    else if (i < 1536) v = bk[i - 768];
    else if (i < 2304) v = bv[i - 1536];
    o[i] = v;
}

// ---------------------------------------------------------------- span means
__global__ __launch_bounds__(256) void spans_kernel(
    const float* __restrict__ txt, const int* __restrict__ starts,
    const int* __restrict__ lens, float* __restrict__ mention,
    bf16_t* __restrict__ mentionb, bf16_t* __restrict__ ctxb)
{
    int m = blockIdx.x;
    int st = starts[m], ln = lens[m];
    int en = st + ln;
    int cs = st - CTX_W; if (cs < 0) cs = 0;
    int ce = en + CTX_W; if (ce > S_LEN - 1) ce = S_LEN - 1;
    int c = threadIdx.x;
    float s0 = 0.f, s1 = 0.f, s2 = 0.f;
    for (int r = st; r <= en; ++r) {
        const float* tr = txt + (size_t)r * D_DIM;
        s0 += tr[c]; s1 += tr[c + 256]; s2 += tr[c + 512];
    }
    float inv = 1.f / (float)(ln + 1);
    float* mp = mention + (size_t)m * D_DIM;
    bf16_t* mb = mentionb + (size_t)m * D_DIM;
    mp[c] = s0 * inv; mp[c + 256] = s1 * inv; mp[c + 512] = s2 * inv;
    mb[c] = (bf16_t)(s0 * inv); mb[c + 256] = (bf16_t)(s1 * inv); mb[c + 512] = (bf16_t)(s2 * inv);

    s0 = 0.f; s1 = 0.f; s2 = 0.f;
    for (int r = cs; r < ce; ++r) {
        const float* tr = txt + (size_t)r * D_DIM;
        s0 += tr[c]; s1 += tr[c + 256]; s2 += tr[c + 512];
    }
    inv = 1.f / (float)(ce - cs);
    bf16_t* cp = ctxb + (size_t)m * D_DIM;
    cp[c] = (bf16_t)(s0 * inv); cp[c + 256] = (bf16_t)(s1 * inv); cp[c + 512] = (bf16_t)(s2 * inv);
}

// ---------------------------------------------------------------- uni_w2 column-mean
__global__ __launch_bounds__(256) void w2bar_kernel(
    const float* __restrict__ uni_w2, const float* __restrict__ uni_b2,
    float* __restrict__ w2bar, float* __restrict__ b2bar)
{
    __shared__ float sbuf[4];
    int d = blockIdx.x;
    float s = 0.f;
    if (d < D_DIM) {
        for (int j = threadIdx.x; j < D_DIM; j += 256) s += uni_w2[(size_t)d * D_DIM + j];
        s = block_reduce_sum(s, sbuf);
        if (threadIdx.x == 0) w2bar[d] = s * (1.f / (float)D_DIM);
    } else {
        for (int j = threadIdx.x; j < D_DIM; j += 256) s += uni_b2[j];
        s = block_reduce_sum(s, sbuf);
        if (threadIdx.x == 0) *b2bar = s * (1.f / (float)D_DIM);
    }
}

// ---------------------------------------------------------------- 2x2 attention (packed stride 3840)
__global__ __launch_bounds__(512) void attn_kernel(
    const bf16_t* __restrict__ qkvm, const bf16_t* __restrict__ qkvc,
    bf16_t* __restrict__ o, int g0)
{
    int lc = blockIdx.x;
    int gg = g0 + lc;
    int m = gg >> 5;
    int h = threadIdx.x >> 6;
    int lane = threadIdx.x & 63;
    const bf16_t* bm = qkvm + (size_t)m * 3840 + h * DH_DIM;
    const bf16_t* bc = qkvc + (size_t)lc * 3840 + h * DH_DIM;

    float s00 = 0.f, s01 = 0.f, s10 = 0.f, s11 = 0.f;
    for (int d = lane; d < DH_DIM; d += 64) {
        float qmv = (float)bm[d], kmv = (float)bm[d + 768];
        float qcv = (float)bc[d], kcv = (float)bc[d + 768];
        s00 += qmv * kmv; s01 += qmv * kcv; s10 += qcv * kmv; s11 += qcv * kcv;
    }
#pragma unroll
    for (int off = 32; off; off >>= 1) {
        s00 += __shfl_down(s00, off); s01 += __shfl_down(s01, off);
        s10 += __shfl_down(s10, off); s11 += __shfl_down(s11, off);
    }
    s00 = __shfl(s00, 0); s01 = __shfl(s01, 0);
    s10 = __shfl(s10, 0); s11 = __shfl(s11, 0);
    const float sc = 0.1020620726159658f;  // 1/sqrt(96)
    s00 *= sc; s01 *= sc; s10 *= sc; s11 *= sc;
    float m0 = fmaxf(s00, s01), m1 = fmaxf(s10, s11);
    float e00 = expf(s00 - m0), e01 = expf(s01 - m0);
    float e10 = expf(s10 - m1), e11 = expf(s11 - m1);
    float i0 = 1.f / (e00 + e01), i1 = 1.f / (e10 + e11);
    float a00 = e00 * i0, a01 = e01 * i0, a10 = e10 * i1, a11 = e11 * i1;

    bf16_t* o0 = o + ((size_t)lc * 2) * D_DIM + h * DH_DIM;
    bf16_t* o1 = o0 + D_DIM;
    for (int d = lane; d < DH_DIM; d += 64) {
        float vmv = (float)bm[d + 1536], vcv = (float)bc[d + 1536];
        o0[d] = (bf16_t)(a00 * vmv + a01 * vcv);
        o1[d] = (bf16_t)(a10 * vmv + a11 * vcv);
    }
}

// ---------------------------------------------------------------- LN1: x1 = LN(res + x1pre); out bf16 + fp8
// candb is the FULL candidate array (indexed by global gg).
__global__ __launch_bounds__(256) void ln1_kernel(
    const bf16_t* __restrict__ x1pre, const float* __restrict__ mention,
    const bf16_t* __restrict__ candb, const float* __restrict__ g,
    const float* __restrict__ b, bf16_t* __restrict__ x1f,
    unsigned char* __restrict__ x1q, int g0)
{
    __shared__ float sbuf[4];
    int r = blockIdx.x;
    int lc = r >> 1, pos = r & 1;
    int gg = g0 + lc, m = gg >> 5;
    int c = threadIdx.x;
    float r0, r1, r2;
    if (pos) {
        const bf16_t* xr = candb + (size_t)gg * D_DIM;
        r0 = (float)xr[c]; r1 = (float)xr[c + 256]; r2 = (float)xr[c + 512];
    } else {
        const float* xr = mention + (size_t)m * D_DIM;
        r0 = xr[c]; r1 = xr[c + 256]; r2 = xr[c + 512];
    }
    const bf16_t* pr = x1pre + (size_t)r * D_DIM;
    float v0 = r0 + (float)pr[c];
    float v1 = r1 + (float)pr[c + 256];
    float v2 = r2 + (float)pr[c + 512];
    float mu = block_reduce_sum(v0 + v1 + v2, sbuf) * (1.f / (float)D_DIM);
    float d0 = v0 - mu, d1 = v1 - mu, d2 = v2 - mu;
    float var = block_reduce_sum(d0 * d0 + d1 * d1 + d2 * d2, sbuf) * (1.f / (float)D_DIM);
    float inv = rsqrtf(var + 1e-5f);
    float o0 = d0 * inv * g[c] + b[c];
    float o1 = d1 * inv * g[c + 256] + b[c + 256];
    float o2 = d2 * inv * g[c + 512] + b[c + 512];
    bf16_t* fp = x1f + (size_t)r * D_DIM;
    fp[c] = (bf16_t)o0; fp[c + 256] = (bf16_t)o1; fp[c + 512] = (bf16_t)o2;
    unsigned char* qp = x1q + (size_t)r * D_DIM;
    qp[c] = (unsigned char)(__builtin_amdgcn_cvt_pk_fp8_f32(o0, o0, 0, false) & 0xff);
    qp[c + 256] = (unsigned char)(__builtin_amdgcn_cvt_pk_fp8_f32(o1, o1, 0, false) & 0xff);
    qp[c + 512] = (unsigned char)(__builtin_amdgcn_cvt_pk_fp8_f32(o2, o2, 0, false) & 0xff);
}

// ---------------------------------------------------------------- fused heads: LN2 + atg + relik + uni
__global__ __launch_bounds__(256) void heads_kernel(
    const bf16_t* __restrict__ x1f, const bf16_t* __restrict__ x2f,
    const float* __restrict__ g2, const float* __restrict__ b2g,
    const float* __restrict__ Ar, const float* __restrict__ Au,
    const bf16_t* __restrict__ qkvc, const float* __restrict__ rw2,
    const float* __restrict__ rb2, const float* __restrict__ w2bar,
    const float* __restrict__ b2bar, float* __restrict__ out, int g0)
{
    __shared__ float sbuf[4];
    int lc = blockIdx.x;
    int gg = g0 + lc, m = gg >> 5;
    int c = threadIdx.x;
    float e[2][3];
#pragma unroll
    for (int rr = 0; rr < 2; ++rr) {
        const bf16_t* x1 = x1f + (size_t)(2 * lc + rr) * D_DIM;
        const bf16_t* x2 = x2f + (size_t)(2 * lc + rr) * D_DIM;
        float v0 = (float)x1[c] + (float)x2[c];
        float v1 = (float)x1[c + 256] + (float)x2[c + 256];
        float v2 = (float)x1[c + 512] + (float)x2[c + 512];
        float mu = block_reduce_sum(v0 + v1 + v2, sbuf) * (1.f / (float)D_DIM);
        float d0 = v0 - mu, d1 = v1 - mu, d2 = v2 - mu;
        float var = block_reduce_sum(d0 * d0 + d1 * d1 + d2 * d2, sbuf) * (1.f / (float)D_DIM);
        float inv = rsqrtf(var + 1e-5f);
        e[rr][0] = d0 * inv * g2[c] + b2g[c];
        e[rr][1] = d1 * inv * g2[c + 256] + b2g[c + 256];
        e[rr][2] = d2 * inv * g2[c + 512] + b2g[c + 512];
    }
    float dd = e[0][0] * e[1][0] + e[0][1] * e[1][1] + e[0][2] * e[1][2];
    float aa = e[0][0] * e[0][0] + e[0][1] * e[0][1] + e[0][2] * e[0][2];
    float bb = e[1][0] * e[1][0] + e[1][1] * e[1][1] + e[1][2] * e[1][2];
    dd = block_reduce_sum(dd, sbuf);
    aa = block_reduce_sum(aa, sbuf);
    bb = block_reduce_sum(bb, sbuf);
    const float* ar = Ar + (size_t)m * D_DIM;
    const bf16_t* br = qkvc + (size_t)lc * 3840 + 2304;
    float rs = fmaxf(ar[c] + (float)br[c], 0.f) * rw2[c]
             + fmaxf(ar[c + 256] + (float)br[c + 256], 0.f) * rw2[c + 256]
             + fmaxf(ar[c + 512] + (float)br[c + 512], 0.f) * rw2[c + 512];
    rs = block_reduce_sum(rs, sbuf);
    const float* au = Au + (size_t)m * D_DIM;
    const bf16_t* bu = qkvc + (size_t)lc * 3840 + 3072;
    float us = fmaxf(au[c] + (float)bu[c], 0.f) * w2bar[c]
             + fmaxf(au[c + 256] + (float)bu[c + 256], 0.f) * w2bar[c + 256]
             + fmaxf(au[c + 512] + (float)bu[c + 512], 0.f) * w2bar[c + 512];
    us = block_reduce_sum(us, sbuf);
    if (threadIdx.x == 0) {
        float n0 = fmaxf(sqrtf(aa), 1e-8f);
        float n1 = fmaxf(sqrtf(bb), 1e-8f);
        out[MK_CNT + gg] = dd / (n0 * n1);
        out[gg] = rs + rb2[0];
        float z = us + *b2bar;
        out[2 * MK_CNT + gg] = 1.f / (1.f + expf(-z));
    }
}

// ---------------------------------------------------------------- host
extern "C" void kernel_launch(void* const* d_in, const int* in_sizes, int n_in,
                              void* d_out, int out_size, void* d_ws, size_t ws_size,
                              hipStream_t stream) {
    const float* text     = (const float*)d_in[0];
    const float* cand     = (const float*)d_in[1];
    const int*   starts   = (const int*)d_in[2];
    const int*   lens     = (const int*)d_in[3];
    const float* relik_w1 = (const float*)d_in[4];
    const float* relik_b1 = (const float*)d_in[5];
    const float* relik_w2 = (const float*)d_in[6];
    const float* relik_b2 = (const float*)d_in[7];
    const float* wq = (const float*)d_in[8];
    const float* bq = (const float*)d_in[9];
    const float* wk = (const float*)d_in[10];
    const float* bk = (const float*)d_in[11];
    const float* wv = (const float*)d_in[12];
    const float* bv = (const float*)d_in[13];
    const float* wo = (const float*)d_in[14];
    const float* bo = (const float*)d_in[15];
    const float* ln1_g = (const float*)d_in[16];
    const float* ln1_b = (const float*)d_in[17];
    const float* ffn_w1 = (const float*)d_in[18];
    const float* ffn_b1 = (const float*)d_in[19];
    const float* ffn_w2 = (const float*)d_in[20];
    const float* ffn_b2 = (const float*)d_in[21];
    const float* ln2_g = (const float*)d_in[22];
    const float* ln2_b = (const float*)d_in[23];
    const float* uni_w1 = (const float*)d_in[24];
    const float* uni_b1 = (const float*)d_in[25];
    const float* uni_w2 = (const float*)d_in[26];
    const float* uni_b2 = (const float*)d_in[27];
    float* out = (float*)d_out;

    const size_t MD = (size_t)M_CNT * D_DIM;
    const size_t DD = (size_t)D_DIM * D_DIM;

    // fixed ~21.3M floats; per chunk 6912*NC floats
    size_t fixed_f = 21300000;
    int NC = 32768;
    while (NC > 128 && (fixed_f + (size_t)NC * 6912) * 4 > ws_size) NC >>= 1;
    const size_t NCD = (size_t)NC * D_DIM;

    float* p = (float*)d_ws;
    float* mention = p; p += MD;
    float* Ar      = p; p += MD;
    float* Au      = p; p += MD;
    float* bqkv5   = p; p += 3840;
    float* w2bar   = p; p += 768;
    float* b2bar   = p; p += 64;
    bf16_t* mentionb = (bf16_t*)p; p += MD / 2;
    bf16_t* ctxb     = (bf16_t*)p; p += MD / 2;
    bf16_t* qkvm     = (bf16_t*)p; p += (size_t)M_CNT * 3840 / 2;
    bf16_t* wcandT   = (bf16_t*)p; p += (size_t)3840 * 768 / 2;
    bf16_t* woT      = (bf16_t*)p; p += DD / 2;
    bf16_t* relikAT  = (bf16_t*)p; p += DD / 2;
    bf16_t* uniAT    = (bf16_t*)p; p += DD / 2;
    unsigned char* w1q = (unsigned char*)p; p += (size_t)3072 * 768 / 4;
    unsigned char* w2q = (unsigned char*)p; p += (size_t)3072 * 768 / 4;
    bf16_t* candb    = (bf16_t*)p; p += (size_t)MK_CNT * D_DIM / 2;
    // per-chunk
    bf16_t* qkvcb = (bf16_t*)p; p += (size_t)NC * 3840 / 2;
    bf16_t* obuf  = (bf16_t*)p; p += 2 * NCD / 2;
    bf16_t* x1pre = (bf16_t*)p; p += 2 * NCD / 2;
    bf16_t* x1f   = (bf16_t*)p; p += 2 * NCD / 2;
    bf16_t* x2f   = (bf16_t*)p; p += 2 * NCD / 2;
    unsigned char* x1q = (unsigned char*)p; p += 2 * NCD / 4;
    unsigned char* hb  = (unsigned char*)p; p += (size_t)2 * NC * 3072 / 4;

    // ---- weight prep ----
    dim3 t768(768 / 32, 768 / 32);
    transpose_bf16<<<t768, 256, 0, stream>>>(wq, wcandT, 768, 768);
    transpose_bf16<<<t768, 256, 0, stream>>>(wk, wcandT + DD, 768, 768);
    transpose_bf16<<<t768, 256, 0, stream>>>(wv, wcandT + 2 * DD, 768, 768);
    transpose_bf16<<<t768, 256, 0, stream>>>(relik_w1 + DD, wcandT + 3 * DD, 768, 768);
    transpose_bf16<<<t768, 256, 0, stream>>>(uni_w1 + DD, wcandT + 4 * DD, 768, 768);
    transpose_bf16<<<t768, 256, 0, stream>>>(wo, woT, 768, 768);
    transpose_bf16<<<t768, 256, 0, stream>>>(relik_w1, relikAT, 768, 768);
    transpose_bf16<<<t768, 256, 0, stream>>>(uni_w1, uniAT, 768, 768);
    transpose_fp8<<<dim3(3072 / 32, 768 / 32), 256, 0, stream>>>(ffn_w1, w1q, 768, 3072);
    transpose_fp8<<<dim3(768 / 32, 3072 / 32), 256, 0, stream>>>(ffn_w2, w2q, 3072, 768);
    pack_bias5<<<15, 256, 0, stream>>>(bq, bk, bv, bqkv5);
    w2bar_kernel<<<D_DIM + 1, 256, 0, stream>>>(uni_w2, uni_b2, w2bar, b2bar);
    cvt_bf16<<<(MK_CNT * D_DIM / 4 + 255) / 256, 256, 0, stream>>>(cand, candb, MK_CNT * D_DIM / 4);

    // ---- per-mention precompute ----
    spans_kernel<<<M_CNT, 256, 0, stream>>>(text, starts, lens, mention, mentionb, ctxb);
    launch_gemm(mentionb, wcandT, bqkv5, qkvm, M_CNT, 768, 3840, false, true, stream);
    launch_gemm(mentionb, relikAT, relik_b1, Ar, M_CNT, 768, 768, false, false, stream);
    launch_gemm(ctxb, uniAT, uni_b1, Au, M_CNT, 768, 768, false, false, stream);

    int nch = MK_CNT / NC;
    for (int c = 0; c < nch; ++c) {
        int g0 = c * NC;
        const bf16_t* cc = candb + (size_t)g0 * D_DIM;
        launch_gemm(cc, wcandT, bqkv5, qkvcb, NC, 768, 3840, false, true, stream);

        attn_kernel<<<NC, 512, 0, stream>>>(qkvm, qkvcb, obuf, g0);

        launch_gemm(obuf, woT, bo, x1pre, 2 * NC, 768, 768, false, true, stream);
        // NOTE: pass FULL candb (kernel indexes by global gg) — round-4 bug was a double offset here
        ln1_kernel<<<2 * NC, 256, 0, stream>>>(x1pre, mention, candb,
                                               ln1_g, ln1_b, x1f, x1q, g0);

        launch_fp8_t<1, 1>(x1q, w1q, ffn_b1, hb, 2 * NC, 768, 3072, stream);
        launch_fp8_t<2, 0>(hb, w2q, ffn_b2, x2f, 2 * NC, 3072, 768, stream);

        heads_kernel<<<NC, 256, 0, stream>>>(x1f, x2f, ln2_g, ln2_b, Ar, Au, qkvcb,
                                             relik_w2, relik_b2, w2bar, b2bar, out, g0);
    }
}

// Round 6
// 1247.284 us; speedup vs baseline: 10.5388x; 1.0661x over previous
//
#include <hip/hip_runtime.h>
#include <math.h>

#define S_LEN 4096
#define D_DIM 768
#define M_CNT 1024
#define K_CNT 32
#define MK_CNT 32768
#define DH_DIM 96
#define CTX_W 10

typedef __bf16 bf16_t;
typedef bf16_t bf16x8 __attribute__((ext_vector_type(8)));
typedef float f32x4 __attribute__((ext_vector_type(4)));
typedef float f32x16 __attribute__((ext_vector_type(16)));
typedef int i32x4 __attribute__((ext_vector_type(4)));
typedef int i32x8 __attribute__((ext_vector_type(8)));

// ---------------------------------------------------------------- block reduce
__device__ __forceinline__ float block_reduce_sum(float v, float* sbuf) {
#pragma unroll
    for (int off = 32; off; off >>= 1) v += __shfl_down(v, off);
    __syncthreads();
    int wave = threadIdx.x >> 6;
    int lane = threadIdx.x & 63;
    if (lane == 0) sbuf[wave] = v;
    __syncthreads();
    return sbuf[0] + sbuf[1] + sbuf[2] + sbuf[3];
}

__device__ __forceinline__ unsigned char to_fp8(float v) {
    return (unsigned char)(__builtin_amdgcn_cvt_pk_fp8_f32(v, v, 0, false) & 0xff);
}

// ---------------------------------------------------------------- bf16 MFMA GEMM
// C[rows,N] = A[rows,Kd] @ Bt[N,Kd]^T. 128x128 tile, BK=64. Grouped row-panel swizzle.
template<int OUT_BF16, int RELU>
__global__ __launch_bounds__(256, 2) void gemm_mfma(
    const bf16_t* __restrict__ A, const bf16_t* __restrict__ Bt,
    const float* __restrict__ bias, void* __restrict__ C,
    int Kd, int N, int nx, int ny)
{
    __shared__ bf16_t As[128 * 64];
    __shared__ bf16_t Bs[128 * 64];
    const int tid = threadIdx.x;
    const int w = tid >> 6, l = tid & 63;
    int per = 8 * nx;
    int g = blockIdx.x / per, rr = blockIdx.x % per;
    int gs = ny - g * 8; if (gs > 8) gs = 8;
    const int row0 = (g * 8 + rr % gs) * 128, col0 = (rr / gs) * 128;

    const int srow = w * 8 + (l >> 3);
    const int gchunk = (l & 7) ^ ((l >> 3) & 7);
    const bf16_t* gA = A + (size_t)(row0 + srow) * Kd + gchunk * 8;
    const bf16_t* gB = Bt + (size_t)(col0 + srow) * Kd + gchunk * 8;

    const int wm = w >> 1, wn = w & 1;
    f32x4 acc[4][4] = {};

    for (int k0 = 0; k0 < Kd; k0 += 64) {
#pragma unroll
        for (int c = 0; c < 4; ++c) {
            __builtin_amdgcn_global_load_lds(
                (const __attribute__((address_space(1))) void*)(gA + (size_t)(c * 32) * Kd + k0),
                (__attribute__((address_space(3))) void*)(As + (c * 256 + w * 64) * 8), 16, 0, 0);
            __builtin_amdgcn_global_load_lds(
                (const __attribute__((address_space(1))) void*)(gB + (size_t)(c * 32) * Kd + k0),
                (__attribute__((address_space(3))) void*)(Bs + (c * 256 + w * 64) * 8), 16, 0, 0);
        }
        __syncthreads();
#pragma unroll
        for (int ks = 0; ks < 2; ++ks) {
            bf16x8 af[4], bfr[4];
#pragma unroll
            for (int i = 0; i < 4; ++i) {
                int arow = wm * 64 + i * 16 + (l & 15);
                int slot = (ks * 4 + (l >> 4)) ^ (l & 7);
                af[i] = *(const bf16x8*)(As + arow * 64 + slot * 8);
                int brow = wn * 64 + i * 16 + (l & 15);
                bfr[i] = *(const bf16x8*)(Bs + brow * 64 + slot * 8);
            }
#pragma unroll
            for (int i = 0; i < 4; ++i)
#pragma unroll
                for (int j = 0; j < 4; ++j)
                    acc[i][j] = __builtin_amdgcn_mfma_f32_16x16x32_bf16(af[i], bfr[j], acc[i][j], 0, 0, 0);
        }
        __syncthreads();
    }

#pragma unroll
    for (int i = 0; i < 4; ++i) {
        int row = row0 + wm * 64 + i * 16 + (l >> 4) * 4;
#pragma unroll
        for (int j = 0; j < 4; ++j) {
            int col = col0 + wn * 64 + j * 16 + (l & 15);
            float bv = bias ? bias[col] : 0.f;
#pragma unroll
            for (int r = 0; r < 4; ++r) {
                float v = acc[i][j][r] + bv;
                if (RELU) v = fmaxf(v, 0.f);
                if (OUT_BF16) ((bf16_t*)C)[(size_t)(row + r) * N + col] = (bf16_t)v;
                else          ((float*)C)[(size_t)(row + r) * N + col] = v;
            }
        }
    }
}

static inline void launch_gemm(const bf16_t* A, const bf16_t* Bt, const float* bias, void* C,
                               int rows, int Kd, int N, bool relu, bool outbf, hipStream_t st) {
    int nx = N / 128, ny = rows / 128;
    dim3 grid(nx * ny);
    if (outbf) {
        if (relu) gemm_mfma<1, 1><<<grid, 256, 0, st>>>(A, Bt, bias, C, Kd, N, nx, ny);
        else      gemm_mfma<1, 0><<<grid, 256, 0, st>>>(A, Bt, bias, C, Kd, N, nx, ny);
    } else {
        if (relu) gemm_mfma<0, 1><<<grid, 256, 0, st>>>(A, Bt, bias, C, Kd, N, nx, ny);
        else      gemm_mfma<0, 0><<<grid, 256, 0, st>>>(A, Bt, bias, C, Kd, N, nx, ny);
    }
}

// ---------------------------------------------------------------- fp8 MX-MFMA GEMM
// C[rows,N] = A[rows,Kd] @ Bt[N,Kd]^T, fp8 e4m3, unit scales. 128x128 tile, BK=128.
// LDS: 16B chunk (row R, global chunk g) at slot R*8 + (g ^ (R&7)) -> conflict-free.
// OMODE: 0=f32, 1=fp8, 2=bf16
template<int OMODE, int RELU>
__global__ __launch_bounds__(256, 2) void gemm_fp8(
    const unsigned char* __restrict__ A, const unsigned char* __restrict__ Bt,
    const float* __restrict__ bias, void* __restrict__ C,
    int Kd, int N, int nx, int ny)
{
    __shared__ unsigned char As[128 * 128];
    __shared__ unsigned char Bs[128 * 128];
    const int tid = threadIdx.x;
    const int w = tid >> 6, l = tid & 63;
    int per = 8 * nx;
    int g = blockIdx.x / per, rrb = blockIdx.x % per;
    int gs = ny - g * 8; if (gs > 8) gs = 8;
    const int row0 = (g * 8 + rrb % gs) * 128, col0 = (rrb / gs) * 128;
    const int wm = w >> 1, wn = w & 1;
    const int SA = 0x7F7F7F7F;          // E8M0 scale = 1.0 in every byte

    const int srow = w * 8 + (l >> 3);
    const int gch = (l & 7) ^ ((l >> 3) & 7);
    const unsigned char* gA = A + (size_t)(row0 + srow) * Kd + gch * 16;
    const unsigned char* gB = Bt + (size_t)(col0 + srow) * Kd + gch * 16;

    f32x16 acc[2][2] = {};

    for (int k0 = 0; k0 < Kd; k0 += 128) {
#pragma unroll
        for (int q = 0; q < 4; ++q) {
            __builtin_amdgcn_global_load_lds(
                (const __attribute__((address_space(1))) void*)(gA + (size_t)(q * 32) * Kd + k0),
                (__attribute__((address_space(3))) void*)(As + (q * 256 + w * 64) * 16), 16, 0, 0);
            __builtin_amdgcn_global_load_lds(
                (const __attribute__((address_space(1))) void*)(gB + (size_t)(q * 32) * Kd + k0),
                (__attribute__((address_space(3))) void*)(Bs + (q * 256 + w * 64) * 16), 16, 0, 0);
        }
        __syncthreads();
#pragma unroll
        for (int s = 0; s < 2; ++s) {
            i32x8 af[2], bfr[2];
            int cb = s * 4 + ((l >> 5) << 1);
#pragma unroll
            for (int i = 0; i < 2; ++i) {
                int row = wm * 64 + i * 32 + (l & 31);
                int sl0 = cb ^ (row & 7);
                int sl1 = (cb + 1) ^ (row & 7);
                i32x4 lo = *(const i32x4*)(As + (row * 8 + sl0) * 16);
                i32x4 hi = *(const i32x4*)(As + (row * 8 + sl1) * 16);
                i32x8 a;
                a[0] = lo[0]; a[1] = lo[1]; a[2] = lo[2]; a[3] = lo[3];
                a[4] = hi[0]; a[5] = hi[1]; a[6] = hi[2]; a[7] = hi[3];
                af[i] = a;
                int colr = wn * 64 + i * 32 + (l & 31);
                int tl0 = cb ^ (colr & 7);
                int tl1 = (cb + 1) ^ (colr & 7);
                lo = *(const i32x4*)(Bs + (colr * 8 + tl0) * 16);
                hi = *(const i32x4*)(Bs + (colr * 8 + tl1) * 16);
                i32x8 b;
                b[0] = lo[0]; b[1] = lo[1]; b[2] = lo[2]; b[3] = lo[3];
                b[4] = hi[0]; b[5] = hi[1]; b[6] = hi[2]; b[7] = hi[3];
                bfr[i] = b;
            }
#pragma unroll
            for (int i = 0; i < 2; ++i)
#pragma unroll
                for (int j = 0; j < 2; ++j)
                    acc[i][j] = __builtin_amdgcn_mfma_scale_f32_32x32x64_f8f6f4(
                        af[i], bfr[j], acc[i][j], 0, 0, 0, SA, 0, SA);
        }
        __syncthreads();
    }

    // 32x32 C/D layout: col=lane&31, row=(reg&3)+8*(reg>>2)+4*(lane>>5)
#pragma unroll
    for (int i = 0; i < 2; ++i) {
        int rbase = row0 + wm * 64 + i * 32 + 4 * (l >> 5);
#pragma unroll
        for (int j = 0; j < 2; ++j) {
            int col = col0 + wn * 64 + j * 32 + (l & 31);
            float bv = bias ? bias[col] : 0.f;
#pragma unroll
            for (int reg = 0; reg < 16; ++reg) {
                int row = rbase + (reg & 3) + 8 * (reg >> 2);
                float v = acc[i][j][reg] + bv;
                if (RELU) v = fmaxf(v, 0.f);
                if (OMODE == 1)
                    ((unsigned char*)C)[(size_t)row * N + col] = to_fp8(v);
                else if (OMODE == 2)
                    ((bf16_t*)C)[(size_t)row * N + col] = (bf16_t)v;
                else
                    ((float*)C)[(size_t)row * N + col] = v;
            }
        }
    }
}

template<int OMODE, int RELU>
static inline void launch_fp8_t(const unsigned char* A, const unsigned char* Bt, const float* bias,
                                void* C, int rows, int Kd, int N, hipStream_t st) {
    int nx = N / 128, ny = rows / 128;
    gemm_fp8<OMODE, RELU><<<dim3(nx * ny), 256, 0, st>>>(A, Bt, bias, C, Kd, N, nx, ny);
}

// ---------------------------------------------------------------- transpose fp32 W[Kd][N] -> bf16 Wt[N][Kd]
__global__ __launch_bounds__(256) void transpose_bf16(
    const float* __restrict__ W, bf16_t* __restrict__ Wt, int Kd, int N)
{
    __shared__ float t[32][33];
    int bx = blockIdx.x * 32, by = blockIdx.y * 32;
    int x = threadIdx.x & 31, y = threadIdx.x >> 5;
#pragma unroll
    for (int yy = y; yy < 32; yy += 8) t[yy][x] = W[(size_t)(by + yy) * N + bx + x];
    __syncthreads();
#pragma unroll
    for (int yy = y; yy < 32; yy += 8) Wt[(size_t)(bx + yy) * Kd + by + x] = (bf16_t)t[x][yy];
}

// ---------------------------------------------------------------- transpose fp32 W[Kd][N] -> fp8 Wt[N][Kd]
__global__ __launch_bounds__(256) void transpose_fp8(
    const float* __restrict__ W, unsigned char* __restrict__ Wt, int Kd, int N)
{
    __shared__ float t[32][33];
    int bx = blockIdx.x * 32, by = blockIdx.y * 32;
    int x = threadIdx.x & 31, y = threadIdx.x >> 5;
#pragma unroll
    for (int yy = y; yy < 32; yy += 8) t[yy][x] = W[(size_t)(by + yy) * N + bx + x];
    __syncthreads();
    int xg = threadIdx.x & 7, yo = threadIdx.x >> 3;
    int lo = __builtin_amdgcn_cvt_pk_fp8_f32(t[xg * 4 + 0][yo], t[xg * 4 + 1][yo], 0, false);
    int both = __builtin_amdgcn_cvt_pk_fp8_f32(t[xg * 4 + 2][yo], t[xg * 4 + 3][yo], lo, true);
    *(int*)(Wt + (size_t)(bx + yo) * Kd + by + xg * 4) = both;
}

// ---------------------------------------------------------------- cand fp32 -> bf16 + fp8
__global__ __launch_bounds__(256) void cvt_cand(
    const float* __restrict__ x, bf16_t* __restrict__ yb,
    unsigned char* __restrict__ yq, int n4)
{
    int i = blockIdx.x * 256 + threadIdx.x;
    if (i < n4) {
        float4 v = ((const float4*)x)[i];
        bf16_t o4[4] = {(bf16_t)v.x, (bf16_t)v.y, (bf16_t)v.z, (bf16_t)v.w};
        ((uint2*)yb)[i] = *(uint2*)o4;
        int lo = __builtin_amdgcn_cvt_pk_fp8_f32(v.x, v.y, 0, false);
        int both = __builtin_amdgcn_cvt_pk_fp8_f32(v.z, v.w, lo, true);
        ((int*)yq)[i] = both;
    }
}

// ---------------------------------------------------------------- bias pack [bq|bk|bv] (2304)
__global__ __launch_bounds__(256) void pack_bias(
    const float* __restrict__ bq, const float* __restrict__ bk,
    const float* __restrict__ bv, float* __restrict__ o)
{
    int i = blockIdx.x * 256 + threadIdx.x;
    if (i < 768) { o[i] = bq[i]; o[i + 768] = bk[i]; o[i + 1536] = bv[i]; }
}

// ---------------------------------------------------------------- span means (fp32 + bf16 + fp8)
__global__ __launch_bounds__(256) void spans_kernel(
    const float* __restrict__ txt, const int* __restrict__ starts,
    const int* __restrict__ lens, float* __restrict__ mention,
    unsigned char* __restrict__ mentionq, bf16_t* __restrict__ mentionb,
    bf16_t* __restrict__ ctxb)
{
    int m = blockIdx.x;
    int st = starts[m], ln = lens[m];
    int en = st + ln;
    int cs = st - CTX_W; if (cs < 0) cs = 0;
    int ce = en + CTX_W; if (ce > S_LEN - 1) ce = S_LEN - 1;
    int c = threadIdx.x;
    float s0 = 0.f, s1 = 0.f, s2 = 0.f;
    for (int r = st; r <= en; ++r) {
        const float* tr = txt + (size_t)r * D_DIM;
        s0 += tr[c]; s1 += tr[c + 256]; s2 += tr[c + 512];
    }
    float inv = 1.f / (float)(ln + 1);
    float v0 = s0 * inv, v1 = s1 * inv, v2 = s2 * inv;
    float* mp = mention + (size_t)m * D_DIM;
    bf16_t* mb = mentionb + (size_t)m * D_DIM;
    unsigned char* mq = mentionq + (size_t)m * D_DIM;
    mp[c] = v0; mp[c + 256] = v1; mp[c + 512] = v2;
    mb[c] = (bf16_t)v0; mb[c + 256] = (bf16_t)v1; mb[c + 512] = (bf16_t)v2;
    mq[c] = to_fp8(v0); mq[c + 256] = to_fp8(v1); mq[c + 512] = to_fp8(v2);

    s0 = 0.f; s1 = 0.f; s2 = 0.f;
    for (int r = cs; r < ce; ++r) {
        const float* tr = txt + (size_t)r * D_DIM;
        s0 += tr[c]; s1 += tr[c + 256]; s2 += tr[c + 512];
    }
    inv = 1.f / (float)(ce - cs);
    bf16_t* cp = ctxb + (size_t)m * D_DIM;
    cp[c] = (bf16_t)(s0 * inv); cp[c + 256] = (bf16_t)(s1 * inv); cp[c + 512] = (bf16_t)(s2 * inv);
}

// ---------------------------------------------------------------- uni_w2 column-mean
__global__ __launch_bounds__(256) void w2bar_kernel(
    const float* __restrict__ uni_w2, const float* __restrict__ uni_b2,
    float* __restrict__ w2bar, float* __restrict__ b2bar)
{
    __shared__ float sbuf[4];
    int d = blockIdx.x;
    float s = 0.f;
    if (d < D_DIM) {
        for (int j = threadIdx.x; j < D_DIM; j += 256) s += uni_w2[(size_t)d * D_DIM + j];
        s = block_reduce_sum(s, sbuf);
        if (threadIdx.x == 0) w2bar[d] = s * (1.f / (float)D_DIM);
    } else {
        for (int j = threadIdx.x; j < D_DIM; j += 256) s += uni_b2[j];
        s = block_reduce_sum(s, sbuf);
        if (threadIdx.x == 0) *b2bar = s * (1.f / (float)D_DIM);
    }
}

// ---------------------------------------------------------------- 2x2 attention (QKV stride 2304, fp8 obuf out)
__global__ __launch_bounds__(512) void attn_kernel(
    const bf16_t* __restrict__ qkvm, const bf16_t* __restrict__ qkvc,
    unsigned char* __restrict__ o, int g0)
{
    int lc = blockIdx.x;
    int gg = g0 + lc;
    int m = gg >> 5;
    int h = threadIdx.x >> 6;
    int lane = threadIdx.x & 63;
    const bf16_t* bm = qkvm + (size_t)m * 2304 + h * DH_DIM;
    const bf16_t* bc = qkvc + (size_t)lc * 2304 + h * DH_DIM;

    float s00 = 0.f, s01 = 0.f, s10 = 0.f, s11 = 0.f;
    for (int d = lane; d < DH_DIM; d += 64) {
        float qmv = (float)bm[d], kmv = (float)bm[d + 768];
        float qcv = (float)bc[d], kcv = (float)bc[d + 768];
        s00 += qmv * kmv; s01 += qmv * kcv; s10 += qcv * kmv; s11 += qcv * kcv;
    }
#pragma unroll
    for (int off = 32; off; off >>= 1) {
        s00 += __shfl_down(s00, off); s01 += __shfl_down(s01, off);
        s10 += __shfl_down(s10, off); s11 += __shfl_down(s11, off);
    }
    s00 = __shfl(s00, 0); s01 = __shfl(s01, 0);
    s10 = __shfl(s10, 0); s11 = __shfl(s11, 0);
    const float sc = 0.1020620726159658f;  // 1/sqrt(96)
    s00 *= sc; s01 *= sc; s10 *= sc; s11 *= sc;
    float m0 = fmaxf(s00, s01), m1 = fmaxf(s10, s11);
    float e00 = expf(s00 - m0), e01 = expf(s01 - m0);
    float e10 = expf(s10 - m1), e11 = expf(s11 - m1);
    float i0 = 1.f / (e00 + e01), i1 = 1.f / (e10 + e11);
    float a00 = e00 * i0, a01 = e01 * i0, a10 = e10 * i1, a11 = e11 * i1;

    unsigned char* o0 = o + ((size_t)lc * 2) * D_DIM + h * DH_DIM;
    unsigned char* o1 = o0 + D_DIM;
    for (int d = lane; d < DH_DIM; d += 64) {
        float vmv = (float)bm[d + 1536], vcv = (float)bc[d + 1536];
        o0[d] = to_fp8(a00 * vmv + a01 * vcv);
        o1[d] = to_fp8(a10 * vmv + a11 * vcv);
    }
}

// ---------------------------------------------------------------- LN1 (full candb indexed by gg)
__global__ __launch_bounds__(256) void ln1_kernel(
    const bf16_t* __restrict__ x1pre, const float* __restrict__ mention,
    const bf16_t* __restrict__ candb, const float* __restrict__ g,
    const float* __restrict__ b, bf16_t* __restrict__ x1f,
    unsigned char* __restrict__ x1q, int g0)
{
    __shared__ float sbuf[4];
    int r = blockIdx.x;
    int lc = r >> 1, pos = r & 1;
    int gg = g0 + lc, m = gg >> 5;
    int c = threadIdx.x;
    float r0, r1, r2;
    if (pos) {
        const bf16_t* xr = candb + (size_t)gg * D_DIM;
        r0 = (float)xr[c]; r1 = (float)xr[c + 256]; r2 = (float)xr[c + 512];
    } else {
        const float* xr = mention + (size_t)m * D_DIM;
        r0 = xr[c]; r1 = xr[c + 256]; r2 = xr[c + 512];
    }
    const bf16_t* pr = x1pre + (size_t)r * D_DIM;
    float v0 = r0 + (float)pr[c];
    float v1 = r1 + (float)pr[c + 256];
    float v2 = r2 + (float)pr[c + 512];
    float mu = block_reduce_sum(v0 + v1 + v2, sbuf) * (1.f / (float)D_DIM);
    float d0 = v0 - mu, d1 = v1 - mu, d2 = v2 - mu;
    float var = block_reduce_sum(d0 * d0 + d1 * d1 + d2 * d2, sbuf) * (1.f / (float)D_DIM);
    float inv = rsqrtf(var + 1e-5f);
    float o0 = d0 * inv * g[c] + b[c];
    float o1 = d1 * inv * g[c + 256] + b[c + 256];
    float o2 = d2 * inv * g[c + 512] + b[c + 512];
    bf16_t* fp = x1f + (size_t)r * D_DIM;
    fp[c] = (bf16_t)o0; fp[c + 256] = (bf16_t)o1; fp[c + 512] = (bf16_t)o2;
    unsigned char* qp = x1q + (size_t)r * D_DIM;
    qp[c] = to_fp8(o0); qp[c + 256] = to_fp8(o1); qp[c + 512] = to_fp8(o2);
}

// ---------------------------------------------------------------- fused heads: LN2 + atg + relik + uni
__global__ __launch_bounds__(256) void heads_kernel(
    const bf16_t* __restrict__ x1f, const bf16_t* __restrict__ x2f,
    const float* __restrict__ g2, const float* __restrict__ b2g,
    const float* __restrict__ Ar, const float* __restrict__ Au,
    const bf16_t* __restrict__ ru, const float* __restrict__ rw2,
    const float* __restrict__ rb2, const float* __restrict__ w2bar,
    const float* __restrict__ b2bar, float* __restrict__ out, int g0)
{
    __shared__ float sbuf[4];
    int lc = blockIdx.x;
    int gg = g0 + lc, m = gg >> 5;
    int c = threadIdx.x;
    float e[2][3];
#pragma unroll
    for (int rr = 0; rr < 2; ++rr) {
        const bf16_t* x1 = x1f + (size_t)(2 * lc + rr) * D_DIM;
        const bf16_t* x2 = x2f + (size_t)(2 * lc + rr) * D_DIM;
        float v0 = (float)x1[c] + (float)x2[c];
        float v1 = (float)x1[c + 256] + (float)x2[c + 256];
        float v2 = (float)x1[c + 512] + (float)x2[c + 512];
        float mu = block_reduce_sum(v0 + v1 + v2, sbuf) * (1.f / (float)D_DIM);
        float d0 = v0 - mu, d1 = v1 - mu, d2 = v2 - mu;
        float var = block_reduce_sum(d0 * d0 + d1 * d1 + d2 * d2, sbuf) * (1.f / (float)D_DIM);
        float inv = rsqrtf(var + 1e-5f);
        e[rr][0] = d0 * inv * g2[c] + b2g[c];
        e[rr][1] = d1 * inv * g2[c + 256] + b2g[c + 256];
        e[rr][2] = d2 * inv * g2[c + 512] + b2g[c + 512];
    }
    float dd = e[0][0] * e[1][0] + e[0][1] * e[1][1] + e[0][2] * e[1][2];
    float aa = e[0][0] * e[0][0] + e[0][1] * e[0][1] + e[0][2] * e[0][2];
    float bb = e[1][0] * e[1][0] + e[1][1] * e[1][1] + e[1][2] * e[1][2];
    dd = block_reduce_sum(dd, sbuf);
    aa = block_reduce_sum(aa, sbuf);
    bb = block_reduce_sum(bb, sbuf);
    const float* ar = Ar + (size_t)m * D_DIM;
    const bf16_t* br = ru + (size_t)lc * 1536;
    float rs = fmaxf(ar[c] + (float)br[c], 0.f) * rw2[c]
             + fmaxf(ar[c + 256] + (float)br[c + 256], 0.f) * rw2[c + 256]
             + fmaxf(ar[c + 512] + (float)br[c + 512], 0.f) * rw2[c + 512];
    rs = block_reduce_sum(rs, sbuf);
    const float* au = Au + (size_t)m * D_DIM;
    const bf16_t* bu = br + 768;
    float us = fmaxf(au[c] + (float)bu[c], 0.f) * w2bar[c]
             + fmaxf(au[c + 256] + (float)bu[c + 256], 0.f) * w2bar[c + 256]
             + fmaxf(au[c + 512] + (float)bu[c + 512], 0.f) * w2bar[c + 512];
    us = block_reduce_sum(us, sbuf);
    if (threadIdx.x == 0) {
        float n0 = fmaxf(sqrtf(aa), 1e-8f);
        float n1 = fmaxf(sqrtf(bb), 1e-8f);
        out[MK_CNT + gg] = dd / (n0 * n1);
        out[gg] = rs + rb2[0];
        float z = us + *b2bar;
        out[2 * MK_CNT + gg] = 1.f / (1.f + expf(-z));
    }
}

// ---------------------------------------------------------------- host
extern "C" void kernel_launch(void* const* d_in, const int* in_sizes, int n_in,
                              void* d_out, int out_size, void* d_ws, size_t ws_size,
                              hipStream_t stream) {
    const float* text     = (const float*)d_in[0];
    const float* cand     = (const float*)d_in[1];
    const int*   starts   = (const int*)d_in[2];
    const int*   lens     = (const int*)d_in[3];
    const float* relik_w1 = (const float*)d_in[4];
    const float* relik_b1 = (const float*)d_in[5];
    const float* relik_w2 = (const float*)d_in[6];
    const float* relik_b2 = (const float*)d_in[7];
    const float* wq = (const float*)d_in[8];
    const float* bq = (const float*)d_in[9];
    const float* wk = (const float*)d_in[10];
    const float* bk = (const float*)d_in[11];
    const float* wv = (const float*)d_in[12];
    const float* bv = (const float*)d_in[13];
    const float* wo = (const float*)d_in[14];
    const float* bo = (const float*)d_in[15];
    const float* ln1_g = (const float*)d_in[16];
    const float* ln1_b = (const float*)d_in[17];
    const float* ffn_w1 = (const float*)d_in[18];
    const float* ffn_b1 = (const float*)d_in[19];
    const float* ffn_w2 = (const float*)d_in[20];
    const float* ffn_b2 = (const float*)d_in[21];
    const float* ln2_g = (const float*)d_in[22];
    const float* ln2_b = (const float*)d_in[23];
    const float* uni_w1 = (const float*)d_in[24];
    const float* uni_b1 = (const float*)d_in[25];
    const float* uni_w2 = (const float*)d_in[26];
    const float* uni_b2 = (const float*)d_in[27];
    float* out = (float*)d_out;

    const size_t MD = (size_t)M_CNT * D_DIM;
    const size_t DD = (size_t)D_DIM * D_DIM;

    // fixed ~26.4M floats; per chunk 6528*NC floats
    size_t fixed_f = 26500000;
    int NC = 32768;
    while (NC > 128 && (fixed_f + (size_t)NC * 6528) * 4 > ws_size) NC >>= 1;
    const size_t NCD = (size_t)NC * D_DIM;

    float* p = (float*)d_ws;
    float* mention = p; p += MD;
    float* Ar      = p; p += MD;
    float* Au      = p; p += MD;
    float* bqkv    = p; p += 2304;
    float* w2bar   = p; p += 768;
    float* b2bar   = p; p += 64;
    bf16_t* mentionb = (bf16_t*)p; p += MD / 2;
    bf16_t* ctxb     = (bf16_t*)p; p += MD / 2;
    unsigned char* mentionq = (unsigned char*)p; p += MD / 4;
    bf16_t* qkvm     = (bf16_t*)p; p += (size_t)M_CNT * 2304 / 2;
    bf16_t* relikAT  = (bf16_t*)p; p += DD / 2;
    bf16_t* uniAT    = (bf16_t*)p; p += DD / 2;
    bf16_t* wruT     = (bf16_t*)p; p += 2 * DD / 2;        // [relikB | uniB] bf16 [1536][768]
    unsigned char* wqkvq = (unsigned char*)p; p += 3 * DD / 4;  // [q|k|v] fp8 [2304][768]
    unsigned char* woq   = (unsigned char*)p; p += DD / 4;
    unsigned char* w1q = (unsigned char*)p; p += (size_t)3072 * 768 / 4;
    unsigned char* w2q = (unsigned char*)p; p += (size_t)3072 * 768 / 4;
    bf16_t* candb    = (bf16_t*)p; p += (size_t)MK_CNT * D_DIM / 2;
    unsigned char* candq = (unsigned char*)p; p += (size_t)MK_CNT * D_DIM / 4;
    // per-chunk
    bf16_t* qkvcb = (bf16_t*)p; p += (size_t)NC * 2304 / 2;
    bf16_t* rucb  = (bf16_t*)p; p += (size_t)NC * 1536 / 2;
    unsigned char* obuf = (unsigned char*)p; p += 2 * NCD / 4;
    bf16_t* x1pre = (bf16_t*)p; p += 2 * NCD / 2;
    bf16_t* x1f   = (bf16_t*)p; p += 2 * NCD / 2;
    bf16_t* x2f   = (bf16_t*)p; p += 2 * NCD / 2;
    unsigned char* x1q = (unsigned char*)p; p += 2 * NCD / 4;
    unsigned char* hb  = (unsigned char*)p; p += (size_t)2 * NC * 3072 / 4;

    // ---- weight prep ----
    dim3 t768(768 / 32, 768 / 32);
    transpose_fp8<<<t768, 256, 0, stream>>>(wq, wqkvq, 768, 768);
    transpose_fp8<<<t768, 256, 0, stream>>>(wk, wqkvq + DD, 768, 768);
    transpose_fp8<<<t768, 256, 0, stream>>>(wv, wqkvq + 2 * DD, 768, 768);
    transpose_fp8<<<t768, 256, 0, stream>>>(wo, woq, 768, 768);
    transpose_bf16<<<t768, 256, 0, stream>>>(relik_w1 + DD, wruT, 768, 768);
    transpose_bf16<<<t768, 256, 0, stream>>>(uni_w1 + DD, wruT + DD, 768, 768);
    transpose_bf16<<<t768, 256, 0, stream>>>(relik_w1, relikAT, 768, 768);
    transpose_bf16<<<t768, 256, 0, stream>>>(uni_w1, uniAT, 768, 768);
    transpose_fp8<<<dim3(3072 / 32, 768 / 32), 256, 0, stream>>>(ffn_w1, w1q, 768, 3072);
    transpose_fp8<<<dim3(768 / 32, 3072 / 32), 256, 0, stream>>>(ffn_w2, w2q, 3072, 768);
    pack_bias<<<3, 256, 0, stream>>>(bq, bk, bv, bqkv);
    w2bar_kernel<<<D_DIM + 1, 256, 0, stream>>>(uni_w2, uni_b2, w2bar, b2bar);
    cvt_cand<<<(MK_CNT * D_DIM / 4 + 255) / 256, 256, 0, stream>>>(cand, candb, candq, MK_CNT * D_DIM / 4);

    // ---- per-mention precompute ----
    spans_kernel<<<M_CNT, 256, 0, stream>>>(text, starts, lens, mention, mentionq, mentionb, ctxb);
    launch_fp8_t<2, 0>(mentionq, wqkvq, bqkv, qkvm, M_CNT, 768, 2304, stream);
    launch_gemm(mentionb, relikAT, relik_b1, Ar, M_CNT, 768, 768, false, false, stream);
    launch_gemm(ctxb, uniAT, uni_b1, Au, M_CNT, 768, 768, false, false, stream);

    int nch = MK_CNT / NC;
    for (int c = 0; c < nch; ++c) {
        int g0 = c * NC;
        // candidate QKV (fp8) + relik/uni (bf16) projections
        launch_fp8_t<2, 0>(candq + (size_t)g0 * D_DIM, wqkvq, bqkv, qkvcb, NC, 768, 2304, stream);
        launch_gemm(candb + (size_t)g0 * D_DIM, wruT, nullptr, rucb, NC, 768, 1536, false, true, stream);

        attn_kernel<<<NC, 512, 0, stream>>>(qkvm, qkvcb, obuf, g0);

        launch_fp8_t<2, 0>(obuf, woq, bo, x1pre, 2 * NC, 768, 768, stream);
        ln1_kernel<<<2 * NC, 256, 0, stream>>>(x1pre, mention, candb,
                                               ln1_g, ln1_b, x1f, x1q, g0);

        launch_fp8_t<1, 1>(x1q, w1q, ffn_b1, hb, 2 * NC, 768, 3072, stream);
        launch_fp8_t<2, 0>(hb, w2q, ffn_b2, x2f, 2 * NC, 3072, 768, stream);

        heads_kernel<<<NC, 256, 0, stream>>>(x1f, x2f, ln2_g, ln2_b, Ar, Au, rucb,
                                             relik_w2, relik_b2, w2bar, b2bar, out, g0);
    }
}

// Round 7
// 1191.630 us; speedup vs baseline: 11.0310x; 1.0467x over previous
//
#include <hip/hip_runtime.h>
#include <math.h>

#define S_LEN 4096
#define D_DIM 768
#define M_CNT 1024
#define K_CNT 32
#define MK_CNT 32768
#define DH_DIM 96
#define CTX_W 10

typedef __bf16 bf16_t;
typedef bf16_t bf16x8 __attribute__((ext_vector_type(8)));
typedef float f32x4 __attribute__((ext_vector_type(4)));
typedef float f32x16 __attribute__((ext_vector_type(16)));
typedef int i32x4 __attribute__((ext_vector_type(4)));
typedef int i32x8 __attribute__((ext_vector_type(8)));

// ---------------------------------------------------------------- reduces
__device__ __forceinline__ float block_reduce_sum(float v, float* sbuf) {
#pragma unroll
    for (int off = 32; off; off >>= 1) v += __shfl_down(v, off);
    __syncthreads();
    int wave = threadIdx.x >> 6;
    int lane = threadIdx.x & 63;
    if (lane == 0) sbuf[wave] = v;
    __syncthreads();
    return sbuf[0] + sbuf[1] + sbuf[2] + sbuf[3];
}

__device__ __forceinline__ float wave_sum(float v) {
#pragma unroll
    for (int off = 32; off; off >>= 1) v += __shfl_down(v, off);
    return __shfl(v, 0);
}

__device__ __forceinline__ unsigned char to_fp8(float v) {
    return (unsigned char)(__builtin_amdgcn_cvt_pk_fp8_f32(v, v, 0, false) & 0xff);
}

// ---------------------------------------------------------------- bf16 MFMA GEMM
template<int OUT_BF16, int RELU>
__global__ __launch_bounds__(256, 2) void gemm_mfma(
    const bf16_t* __restrict__ A, const bf16_t* __restrict__ Bt,
    const float* __restrict__ bias, void* __restrict__ C,
    int Kd, int N, int nx, int ny)
{
    __shared__ bf16_t As[128 * 64];
    __shared__ bf16_t Bs[128 * 64];
    const int tid = threadIdx.x;
    const int w = tid >> 6, l = tid & 63;
    int per = 8 * nx;
    int g = blockIdx.x / per, rr = blockIdx.x % per;
    int gs = ny - g * 8; if (gs > 8) gs = 8;
    const int row0 = (g * 8 + rr % gs) * 128, col0 = (rr / gs) * 128;

    const int srow = w * 8 + (l >> 3);
    const int gchunk = (l & 7) ^ ((l >> 3) & 7);
    const bf16_t* gA = A + (size_t)(row0 + srow) * Kd + gchunk * 8;
    const bf16_t* gB = Bt + (size_t)(col0 + srow) * Kd + gchunk * 8;

    const int wm = w >> 1, wn = w & 1;
    f32x4 acc[4][4] = {};

    for (int k0 = 0; k0 < Kd; k0 += 64) {
#pragma unroll
        for (int c = 0; c < 4; ++c) {
            __builtin_amdgcn_global_load_lds(
                (const __attribute__((address_space(1))) void*)(gA + (size_t)(c * 32) * Kd + k0),
                (__attribute__((address_space(3))) void*)(As + (c * 256 + w * 64) * 8), 16, 0, 0);
            __builtin_amdgcn_global_load_lds(
                (const __attribute__((address_space(1))) void*)(gB + (size_t)(c * 32) * Kd + k0),
                (__attribute__((address_space(3))) void*)(Bs + (c * 256 + w * 64) * 8), 16, 0, 0);
        }
        __syncthreads();
#pragma unroll
        for (int ks = 0; ks < 2; ++ks) {
            bf16x8 af[4], bfr[4];
#pragma unroll
            for (int i = 0; i < 4; ++i) {
                int arow = wm * 64 + i * 16 + (l & 15);
                int slot = (ks * 4 + (l >> 4)) ^ (l & 7);
                af[i] = *(const bf16x8*)(As + arow * 64 + slot * 8);
                int brow = wn * 64 + i * 16 + (l & 15);
                bfr[i] = *(const bf16x8*)(Bs + brow * 64 + slot * 8);
            }
#pragma unroll
            for (int i = 0; i < 4; ++i)
#pragma unroll
                for (int j = 0; j < 4; ++j)
                    acc[i][j] = __builtin_amdgcn_mfma_f32_16x16x32_bf16(af[i], bfr[j], acc[i][j], 0, 0, 0);
        }
        __syncthreads();
    }

#pragma unroll
    for (int i = 0; i < 4; ++i) {
        int row = row0 + wm * 64 + i * 16 + (l >> 4) * 4;
#pragma unroll
        for (int j = 0; j < 4; ++j) {
            int col = col0 + wn * 64 + j * 16 + (l & 15);
            float bv = bias ? bias[col] : 0.f;
#pragma unroll
            for (int r = 0; r < 4; ++r) {
                float v = acc[i][j][r] + bv;
                if (RELU) v = fmaxf(v, 0.f);
                if (OUT_BF16) ((bf16_t*)C)[(size_t)(row + r) * N + col] = (bf16_t)v;
                else          ((float*)C)[(size_t)(row + r) * N + col] = v;
            }
        }
    }
}

static inline void launch_gemm(const bf16_t* A, const bf16_t* Bt, const float* bias, void* C,
                               int rows, int Kd, int N, bool relu, bool outbf, hipStream_t st) {
    int nx = N / 128, ny = rows / 128;
    dim3 grid(nx * ny);
    if (outbf) {
        if (relu) gemm_mfma<1, 1><<<grid, 256, 0, st>>>(A, Bt, bias, C, Kd, N, nx, ny);
        else      gemm_mfma<1, 0><<<grid, 256, 0, st>>>(A, Bt, bias, C, Kd, N, nx, ny);
    } else {
        if (relu) gemm_mfma<0, 1><<<grid, 256, 0, st>>>(A, Bt, bias, C, Kd, N, nx, ny);
        else      gemm_mfma<0, 0><<<grid, 256, 0, st>>>(A, Bt, bias, C, Kd, N, nx, ny);
    }
}

// ---------------------------------------------------------------- fp8 MX-MFMA GEMM
// OMODE: 0=f32, 1=fp8, 2=bf16. RESID: add bf16 residual at [row][col] before store.
template<int OMODE, int RELU, int RESID>
__global__ __launch_bounds__(256, 2) void gemm_fp8(
    const unsigned char* __restrict__ A, const unsigned char* __restrict__ Bt,
    const float* __restrict__ bias, void* __restrict__ C,
    const bf16_t* __restrict__ resid,
    int Kd, int N, int nx, int ny)
{
    __shared__ unsigned char As[128 * 128];
    __shared__ unsigned char Bs[128 * 128];
    const int tid = threadIdx.x;
    const int w = tid >> 6, l = tid & 63;
    int per = 8 * nx;
    int g = blockIdx.x / per, rrb = blockIdx.x % per;
    int gs = ny - g * 8; if (gs > 8) gs = 8;
    const int row0 = (g * 8 + rrb % gs) * 128, col0 = (rrb / gs) * 128;
    const int wm = w >> 1, wn = w & 1;
    const int SA = 0x7F7F7F7F;          // E8M0 scale = 1.0 in every byte

    const int srow = w * 8 + (l >> 3);
    const int gch = (l & 7) ^ ((l >> 3) & 7);
    const unsigned char* gA = A + (size_t)(row0 + srow) * Kd + gch * 16;
    const unsigned char* gB = Bt + (size_t)(col0 + srow) * Kd + gch * 16;

    f32x16 acc[2][2] = {};

    for (int k0 = 0; k0 < Kd; k0 += 128) {
#pragma unroll
        for (int q = 0; q < 4; ++q) {
            __builtin_amdgcn_global_load_lds(
                (const __attribute__((address_space(1))) void*)(gA + (size_t)(q * 32) * Kd + k0),
                (__attribute__((address_space(3))) void*)(As + (q * 256 + w * 64) * 16), 16, 0, 0);
            __builtin_amdgcn_global_load_lds(
                (const __attribute__((address_space(1))) void*)(gB + (size_t)(q * 32) * Kd + k0),
                (__attribute__((address_space(3))) void*)(Bs + (q * 256 + w * 64) * 16), 16, 0, 0);
        }
        __syncthreads();
#pragma unroll
        for (int s = 0; s < 2; ++s) {
            i32x8 af[2], bfr[2];
            int cb = s * 4 + ((l >> 5) << 1);
#pragma unroll
            for (int i = 0; i < 2; ++i) {
                int row = wm * 64 + i * 32 + (l & 31);
                int sl0 = cb ^ (row & 7);
                int sl1 = (cb + 1) ^ (row & 7);
                i32x4 lo = *(const i32x4*)(As + (row * 8 + sl0) * 16);
                i32x4 hi = *(const i32x4*)(As + (row * 8 + sl1) * 16);
                i32x8 a;
                a[0] = lo[0]; a[1] = lo[1]; a[2] = lo[2]; a[3] = lo[3];
                a[4] = hi[0]; a[5] = hi[1]; a[6] = hi[2]; a[7] = hi[3];
                af[i] = a;
                int colr = wn * 64 + i * 32 + (l & 31);
                int tl0 = cb ^ (colr & 7);
                int tl1 = (cb + 1) ^ (colr & 7);
                lo = *(const i32x4*)(Bs + (colr * 8 + tl0) * 16);
                hi = *(const i32x4*)(Bs + (colr * 8 + tl1) * 16);
                i32x8 b;
                b[0] = lo[0]; b[1] = lo[1]; b[2] = lo[2]; b[3] = lo[3];
                b[4] = hi[0]; b[5] = hi[1]; b[6] = hi[2]; b[7] = hi[3];
                bfr[i] = b;
            }
#pragma unroll
            for (int i = 0; i < 2; ++i)
#pragma unroll
                for (int j = 0; j < 2; ++j)
                    acc[i][j] = __builtin_amdgcn_mfma_scale_f32_32x32x64_f8f6f4(
                        af[i], bfr[j], acc[i][j], 0, 0, 0, SA, 0, SA);
        }
        __syncthreads();
    }

    // 32x32 C/D layout: col=lane&31, row=(reg&3)+8*(reg>>2)+4*(lane>>5)
#pragma unroll
    for (int i = 0; i < 2; ++i) {
        int rbase = row0 + wm * 64 + i * 32 + 4 * (l >> 5);
#pragma unroll
        for (int j = 0; j < 2; ++j) {
            int col = col0 + wn * 64 + j * 32 + (l & 31);
            float bv = bias ? bias[col] : 0.f;
#pragma unroll
            for (int reg = 0; reg < 16; ++reg) {
                int row = rbase + (reg & 3) + 8 * (reg >> 2);
                float v = acc[i][j][reg] + bv;
                if (RESID) v += (float)resid[(size_t)row * N + col];
                if (RELU) v = fmaxf(v, 0.f);
                if (OMODE == 1)
                    ((unsigned char*)C)[(size_t)row * N + col] = to_fp8(v);
                else if (OMODE == 2)
                    ((bf16_t*)C)[(size_t)row * N + col] = (bf16_t)v;
                else
                    ((float*)C)[(size_t)row * N + col] = v;
            }
        }
    }
}

template<int OMODE, int RELU, int RESID>
static inline void launch_fp8_t(const unsigned char* A, const unsigned char* Bt, const float* bias,
                                void* C, const bf16_t* resid, int rows, int Kd, int N, hipStream_t st) {
    int nx = N / 128, ny = rows / 128;
    gemm_fp8<OMODE, RELU, RESID><<<dim3(nx * ny), 256, 0, st>>>(A, Bt, bias, C, resid, Kd, N, nx, ny);
}

// ---------------------------------------------------------------- transpose fp32 W[Kd][N] -> bf16 Wt[N][Kd]
__global__ __launch_bounds__(256) void transpose_bf16(
    const float* __restrict__ W, bf16_t* __restrict__ Wt, int Kd, int N)
{
    __shared__ float t[32][33];
    int bx = blockIdx.x * 32, by = blockIdx.y * 32;
    int x = threadIdx.x & 31, y = threadIdx.x >> 5;
#pragma unroll
    for (int yy = y; yy < 32; yy += 8) t[yy][x] = W[(size_t)(by + yy) * N + bx + x];
    __syncthreads();
#pragma unroll
    for (int yy = y; yy < 32; yy += 8) Wt[(size_t)(bx + yy) * Kd + by + x] = (bf16_t)t[x][yy];
}

// ---------------------------------------------------------------- transpose fp32 W[Kd][N] -> fp8 Wt[N][Kd]
__global__ __launch_bounds__(256) void transpose_fp8(
    const float* __restrict__ W, unsigned char* __restrict__ Wt, int Kd, int N)
{
    __shared__ float t[32][33];
    int bx = blockIdx.x * 32, by = blockIdx.y * 32;
    int x = threadIdx.x & 31, y = threadIdx.x >> 5;
#pragma unroll
    for (int yy = y; yy < 32; yy += 8) t[yy][x] = W[(size_t)(by + yy) * N + bx + x];
    __syncthreads();
    int xg = threadIdx.x & 7, yo = threadIdx.x >> 3;
    int lo = __builtin_amdgcn_cvt_pk_fp8_f32(t[xg * 4 + 0][yo], t[xg * 4 + 1][yo], 0, false);
    int both = __builtin_amdgcn_cvt_pk_fp8_f32(t[xg * 4 + 2][yo], t[xg * 4 + 3][yo], lo, true);
    *(int*)(Wt + (size_t)(bx + yo) * Kd + by + xg * 4) = both;
}

// ---------------------------------------------------------------- cand fp32 -> bf16 + fp8
__global__ __launch_bounds__(256) void cvt_cand(
    const float* __restrict__ x, bf16_t* __restrict__ yb,
    unsigned char* __restrict__ yq, int n4)
{
    int i = blockIdx.x * 256 + threadIdx.x;
    if (i < n4) {
        float4 v = ((const float4*)x)[i];
        bf16_t o4[4] = {(bf16_t)v.x, (bf16_t)v.y, (bf16_t)v.z, (bf16_t)v.w};
        ((uint2*)yb)[i] = *(uint2*)o4;
        int lo = __builtin_amdgcn_cvt_pk_fp8_f32(v.x, v.y, 0, false);
        int both = __builtin_amdgcn_cvt_pk_fp8_f32(v.z, v.w, lo, true);
        ((int*)yq)[i] = both;
    }
}

// ---------------------------------------------------------------- bias pack [bq|bk|bv] (2304)
__global__ __launch_bounds__(256) void pack_bias(
    const float* __restrict__ bq, const float* __restrict__ bk,
    const float* __restrict__ bv, float* __restrict__ o)
{
    int i = blockIdx.x * 256 + threadIdx.x;
    if (i < 768) { o[i] = bq[i]; o[i + 768] = bk[i]; o[i + 1536] = bv[i]; }
}

// ---------------------------------------------------------------- span means (fp32 + bf16 + fp8)
__global__ __launch_bounds__(256) void spans_kernel(
    const float* __restrict__ txt, const int* __restrict__ starts,
    const int* __restrict__ lens, float* __restrict__ mention,
    unsigned char* __restrict__ mentionq, bf16_t* __restrict__ mentionb,
    bf16_t* __restrict__ ctxb)
{
    int m = blockIdx.x;
    int st = starts[m], ln = lens[m];
    int en = st + ln;
    int cs = st - CTX_W; if (cs < 0) cs = 0;
    int ce = en + CTX_W; if (ce > S_LEN - 1) ce = S_LEN - 1;
    int c = threadIdx.x;
    float s0 = 0.f, s1 = 0.f, s2 = 0.f;
    for (int r = st; r <= en; ++r) {
        const float* tr = txt + (size_t)r * D_DIM;
        s0 += tr[c]; s1 += tr[c + 256]; s2 += tr[c + 512];
    }
    float inv = 1.f / (float)(ln + 1);
    float v0 = s0 * inv, v1 = s1 * inv, v2 = s2 * inv;
    float* mp = mention + (size_t)m * D_DIM;
    bf16_t* mb = mentionb + (size_t)m * D_DIM;
    unsigned char* mq = mentionq + (size_t)m * D_DIM;
    mp[c] = v0; mp[c + 256] = v1; mp[c + 512] = v2;
    mb[c] = (bf16_t)v0; mb[c + 256] = (bf16_t)v1; mb[c + 512] = (bf16_t)v2;
    mq[c] = to_fp8(v0); mq[c + 256] = to_fp8(v1); mq[c + 512] = to_fp8(v2);

    s0 = 0.f; s1 = 0.f; s2 = 0.f;
    for (int r = cs; r < ce; ++r) {
        const float* tr = txt + (size_t)r * D_DIM;
        s0 += tr[c]; s1 += tr[c + 256]; s2 += tr[c + 512];
    }
    inv = 1.f / (float)(ce - cs);
    bf16_t* cp = ctxb + (size_t)m * D_DIM;
    cp[c] = (bf16_t)(s0 * inv); cp[c + 256] = (bf16_t)(s1 * inv); cp[c + 512] = (bf16_t)(s2 * inv);
}

// ---------------------------------------------------------------- uni_w2 column-mean
__global__ __launch_bounds__(256) void w2bar_kernel(
    const float* __restrict__ uni_w2, const float* __restrict__ uni_b2,
    float* __restrict__ w2bar, float* __restrict__ b2bar)
{
    __shared__ float sbuf[4];
    int d = blockIdx.x;
    float s = 0.f;
    if (d < D_DIM) {
        for (int j = threadIdx.x; j < D_DIM; j += 256) s += uni_w2[(size_t)d * D_DIM + j];
        s = block_reduce_sum(s, sbuf);
        if (threadIdx.x == 0) w2bar[d] = s * (1.f / (float)D_DIM);
    } else {
        for (int j = threadIdx.x; j < D_DIM; j += 256) s += uni_b2[j];
        s = block_reduce_sum(s, sbuf);
        if (threadIdx.x == 0) *b2bar = s * (1.f / (float)D_DIM);
    }
}

// ---------------------------------------------------------------- 2x2 attention (QKV stride 2304, fp8 obuf out)
__global__ __launch_bounds__(512) void attn_kernel(
    const bf16_t* __restrict__ qkvm, const bf16_t* __restrict__ qkvc,
    unsigned char* __restrict__ o, int g0)
{
    int lc = blockIdx.x;
    int gg = g0 + lc;
    int m = gg >> 5;
    int h = threadIdx.x >> 6;
    int lane = threadIdx.x & 63;
    const bf16_t* bm = qkvm + (size_t)m * 2304 + h * DH_DIM;
    const bf16_t* bc = qkvc + (size_t)lc * 2304 + h * DH_DIM;

    float s00 = 0.f, s01 = 0.f, s10 = 0.f, s11 = 0.f;
    for (int d = lane; d < DH_DIM; d += 64) {
        float qmv = (float)bm[d], kmv = (float)bm[d + 768];
        float qcv = (float)bc[d], kcv = (float)bc[d + 768];
        s00 += qmv * kmv; s01 += qmv * kcv; s10 += qcv * kmv; s11 += qcv * kcv;
    }
#pragma unroll
    for (int off = 32; off; off >>= 1) {
        s00 += __shfl_down(s00, off); s01 += __shfl_down(s01, off);
        s10 += __shfl_down(s10, off); s11 += __shfl_down(s11, off);
    }
    s00 = __shfl(s00, 0); s01 = __shfl(s01, 0);
    s10 = __shfl(s10, 0); s11 = __shfl(s11, 0);
    const float sc = 0.1020620726159658f;  // 1/sqrt(96)
    s00 *= sc; s01 *= sc; s10 *= sc; s11 *= sc;
    float m0 = fmaxf(s00, s01), m1 = fmaxf(s10, s11);
    float e00 = expf(s00 - m0), e01 = expf(s01 - m0);
    float e10 = expf(s10 - m1), e11 = expf(s11 - m1);
    float i0 = 1.f / (e00 + e01), i1 = 1.f / (e10 + e11);
    float a00 = e00 * i0, a01 = e01 * i0, a10 = e10 * i1, a11 = e11 * i1;

    unsigned char* o0 = o + ((size_t)lc * 2) * D_DIM + h * DH_DIM;
    unsigned char* o1 = o0 + D_DIM;
    for (int d = lane; d < DH_DIM; d += 64) {
        float vmv = (float)bm[d + 1536], vcv = (float)bc[d + 1536];
        o0[d] = to_fp8(a00 * vmv + a01 * vcv);
        o1[d] = to_fp8(a10 * vmv + a11 * vcv);
    }
}

// ---------------------------------------------------------------- LN1 (wave-per-row; full candb indexed by gg)
__global__ __launch_bounds__(256) void ln1_kernel(
    const bf16_t* __restrict__ x1pre, const float* __restrict__ mention,
    const bf16_t* __restrict__ candb, const float* __restrict__ g,
    const float* __restrict__ b, bf16_t* __restrict__ x1f,
    unsigned char* __restrict__ x1q, int g0)
{
    int w = threadIdx.x >> 6, l = threadIdx.x & 63;
    int r = blockIdx.x * 4 + w;
    int lc = r >> 1, pos = r & 1;
    int gg = g0 + lc, m = gg >> 5;
    float v[12];
    const bf16_t* pr = x1pre + (size_t)r * D_DIM;
    if (pos) {
        const bf16_t* xr = candb + (size_t)gg * D_DIM;
#pragma unroll
        for (int i = 0; i < 12; ++i) { int j = l + i * 64; v[i] = (float)xr[j] + (float)pr[j]; }
    } else {
        const float* xr = mention + (size_t)m * D_DIM;
#pragma unroll
        for (int i = 0; i < 12; ++i) { int j = l + i * 64; v[i] = xr[j] + (float)pr[j]; }
    }
    float s = 0.f;
#pragma unroll
    for (int i = 0; i < 12; ++i) s += v[i];
    float mu = wave_sum(s) * (1.f / (float)D_DIM);
    float vv = 0.f;
#pragma unroll
    for (int i = 0; i < 12; ++i) { float d = v[i] - mu; vv += d * d; }
    float var = wave_sum(vv) * (1.f / (float)D_DIM);
    float inv = rsqrtf(var + 1e-5f);
    bf16_t* fp = x1f + (size_t)r * D_DIM;
    unsigned char* qp = x1q + (size_t)r * D_DIM;
#pragma unroll
    for (int i = 0; i < 12; ++i) {
        int j = l + i * 64;
        float o = (v[i] - mu) * inv * g[j] + b[j];
        fp[j] = (bf16_t)o;
        qp[j] = to_fp8(o);
    }
}

// ---------------------------------------------------------------- fused heads (wave-per-pair): LN2 + atg + relik + uni
// y = x1 + f (bf16, already summed by FFN2 epilogue)
__global__ __launch_bounds__(256) void heads_kernel(
    const bf16_t* __restrict__ y,
    const float* __restrict__ g2, const float* __restrict__ b2g,
    const float* __restrict__ Ar, const float* __restrict__ Au,
    const bf16_t* __restrict__ ru, const float* __restrict__ rw2,
    const float* __restrict__ rb2, const float* __restrict__ w2bar,
    const float* __restrict__ b2bar, float* __restrict__ out, int g0)
{
    int w = threadIdx.x >> 6, l = threadIdx.x & 63;
    int lc = blockIdx.x * 4 + w;
    int gg = g0 + lc, m = gg >> 5;
    const bf16_t* y0 = y + (size_t)(2 * lc) * D_DIM;
    const bf16_t* y1 = y0 + D_DIM;
    float v0[12], v1[12];
    float s0 = 0.f, s1 = 0.f;
#pragma unroll
    for (int i = 0; i < 12; ++i) {
        int j = l + i * 64;
        v0[i] = (float)y0[j]; v1[i] = (float)y1[j];
        s0 += v0[i]; s1 += v1[i];
    }
    float mu0 = wave_sum(s0) * (1.f / (float)D_DIM);
    float mu1 = wave_sum(s1) * (1.f / (float)D_DIM);
    float q0 = 0.f, q1 = 0.f;
#pragma unroll
    for (int i = 0; i < 12; ++i) {
        float d0 = v0[i] - mu0, d1 = v1[i] - mu1;
        q0 += d0 * d0; q1 += d1 * d1;
    }
    float inv0 = rsqrtf(wave_sum(q0) * (1.f / (float)D_DIM) + 1e-5f);
    float inv1 = rsqrtf(wave_sum(q1) * (1.f / (float)D_DIM) + 1e-5f);

    const float* ar = Ar + (size_t)m * D_DIM;
    const float* au = Au + (size_t)m * D_DIM;
    const bf16_t* br = ru + (size_t)lc * 1536;
    const bf16_t* bu = br + 768;

    float dd = 0.f, aa = 0.f, bb = 0.f, rs = 0.f, us = 0.f;
#pragma unroll
    for (int i = 0; i < 12; ++i) {
        int j = l + i * 64;
        float e0 = (v0[i] - mu0) * inv0 * g2[j] + b2g[j];
        float e1 = (v1[i] - mu1) * inv1 * g2[j] + b2g[j];
        dd += e0 * e1; aa += e0 * e0; bb += e1 * e1;
        rs += fmaxf(ar[j] + (float)br[j], 0.f) * rw2[j];
        us += fmaxf(au[j] + (float)bu[j], 0.f) * w2bar[j];
    }
    dd = wave_sum(dd); aa = wave_sum(aa); bb = wave_sum(bb);
    rs = wave_sum(rs); us = wave_sum(us);
    if (l == 0) {
        float n0 = fmaxf(sqrtf(aa), 1e-8f);
        float n1 = fmaxf(sqrtf(bb), 1e-8f);
        out[MK_CNT + gg] = dd / (n0 * n1);
        out[gg] = rs + rb2[0];
        float z = us + *b2bar;
        out[2 * MK_CNT + gg] = 1.f / (1.f + expf(-z));
    }
}

// ---------------------------------------------------------------- host
extern "C" void kernel_launch(void* const* d_in, const int* in_sizes, int n_in,
                              void* d_out, int out_size, void* d_ws, size_t ws_size,
                              hipStream_t stream) {
    const float* text     = (const float*)d_in[0];
    const float* cand     = (const float*)d_in[1];
    const int*   starts   = (const int*)d_in[2];
    const int*   lens     = (const int*)d_in[3];
    const float* relik_w1 = (const float*)d_in[4];
    const float* relik_b1 = (const float*)d_in[5];
    const float* relik_w2 = (const float*)d_in[6];
    const float* relik_b2 = (const float*)d_in[7];
    const float* wq = (const float*)d_in[8];
    const float* bq = (const float*)d_in[9];
    const float* wk = (const float*)d_in[10];
    const float* bk = (const float*)d_in[11];
    const float* wv = (const float*)d_in[12];
    const float* bv = (const float*)d_in[13];
    const float* wo = (const float*)d_in[14];
    const float* bo = (const float*)d_in[15];
    const float* ln1_g = (const float*)d_in[16];
    const float* ln1_b = (const float*)d_in[17];
    const float* ffn_w1 = (const float*)d_in[18];
    const float* ffn_b1 = (const float*)d_in[19];
    const float* ffn_w2 = (const float*)d_in[20];
    const float* ffn_b2 = (const float*)d_in[21];
    const float* ln2_g = (const float*)d_in[22];
    const float* ln2_b = (const float*)d_in[23];
    const float* uni_w1 = (const float*)d_in[24];
    const float* uni_b1 = (const float*)d_in[25];
    const float* uni_w2 = (const float*)d_in[26];
    const float* uni_b2 = (const float*)d_in[27];
    float* out = (float*)d_out;

    const size_t MD = (size_t)M_CNT * D_DIM;
    const size_t DD = (size_t)D_DIM * D_DIM;

    // fixed ~26.4M floats; per chunk 6528*NC floats
    size_t fixed_f = 26500000;
    int NC = 32768;
    while (NC > 128 && (fixed_f + (size_t)NC * 6528) * 4 > ws_size) NC >>= 1;
    const size_t NCD = (size_t)NC * D_DIM;

    float* p = (float*)d_ws;
    float* mention = p; p += MD;
    float* Ar      = p; p += MD;
    float* Au      = p; p += MD;
    float* bqkv    = p; p += 2304;
    float* w2bar   = p; p += 768;
    float* b2bar   = p; p += 64;
    bf16_t* mentionb = (bf16_t*)p; p += MD / 2;
    bf16_t* ctxb     = (bf16_t*)p; p += MD / 2;
    unsigned char* mentionq = (unsigned char*)p; p += MD / 4;
    bf16_t* qkvm     = (bf16_t*)p; p += (size_t)M_CNT * 2304 / 2;
    bf16_t* relikAT  = (bf16_t*)p; p += DD / 2;
    bf16_t* uniAT    = (bf16_t*)p; p += DD / 2;
    bf16_t* wruT     = (bf16_t*)p; p += 2 * DD / 2;        // [relikB | uniB] bf16 [1536][768]
    unsigned char* wqkvq = (unsigned char*)p; p += 3 * DD / 4;  // [q|k|v] fp8 [2304][768]
    unsigned char* woq   = (unsigned char*)p; p += DD / 4;
    unsigned char* w1q = (unsigned char*)p; p += (size_t)3072 * 768 / 4;
    unsigned char* w2q = (unsigned char*)p; p += (size_t)3072 * 768 / 4;
    bf16_t* candb    = (bf16_t*)p; p += (size_t)MK_CNT * D_DIM / 2;
    unsigned char* candq = (unsigned char*)p; p += (size_t)MK_CNT * D_DIM / 4;
    // per-chunk
    bf16_t* qkvcb = (bf16_t*)p; p += (size_t)NC * 2304 / 2;
    bf16_t* rucb  = (bf16_t*)p; p += (size_t)NC * 1536 / 2;
    unsigned char* obuf = (unsigned char*)p; p += 2 * NCD / 4;
    bf16_t* x1pre = (bf16_t*)p; p += 2 * NCD / 2;
    bf16_t* x1f   = (bf16_t*)p; p += 2 * NCD / 2;
    bf16_t* x2f   = (bf16_t*)p; p += 2 * NCD / 2;
    unsigned char* x1q = (unsigned char*)p; p += 2 * NCD / 4;
    unsigned char* hb  = (unsigned char*)p; p += (size_t)2 * NC * 3072 / 4;

    // ---- weight prep ----
    dim3 t768(768 / 32, 768 / 32);
    transpose_fp8<<<t768, 256, 0, stream>>>(wq, wqkvq, 768, 768);
    transpose_fp8<<<t768, 256, 0, stream>>>(wk, wqkvq + DD, 768, 768);
    transpose_fp8<<<t768, 256, 0, stream>>>(wv, wqkvq + 2 * DD, 768, 768);
    transpose_fp8<<<t768, 256, 0, stream>>>(wo, woq, 768, 768);
    transpose_bf16<<<t768, 256, 0, stream>>>(relik_w1 + DD, wruT, 768, 768);
    transpose_bf16<<<t768, 256, 0, stream>>>(uni_w1 + DD, wruT + DD, 768, 768);
    transpose_bf16<<<t768, 256, 0, stream>>>(relik_w1, relikAT, 768, 768);
    transpose_bf16<<<t768, 256, 0, stream>>>(uni_w1, uniAT, 768, 768);
    transpose_fp8<<<dim3(3072 / 32, 768 / 32), 256, 0, stream>>>(ffn_w1, w1q, 768, 3072);
    transpose_fp8<<<dim3(768 / 32, 3072 / 32), 256, 0, stream>>>(ffn_w2, w2q, 3072, 768);
    pack_bias<<<3, 256, 0, stream>>>(bq, bk, bv, bqkv);
    w2bar_kernel<<<D_DIM + 1, 256, 0, stream>>>(uni_w2, uni_b2, w2bar, b2bar);
    cvt_cand<<<(MK_CNT * D_DIM / 4 + 255) / 256, 256, 0, stream>>>(cand, candb, candq, MK_CNT * D_DIM / 4);

    // ---- per-mention precompute ----
    spans_kernel<<<M_CNT, 256, 0, stream>>>(text, starts, lens, mention, mentionq, mentionb, ctxb);
    launch_fp8_t<2, 0, 0>(mentionq, wqkvq, bqkv, qkvm, nullptr, M_CNT, 768, 2304, stream);
    launch_gemm(mentionb, relikAT, relik_b1, Ar, M_CNT, 768, 768, false, false, stream);
    launch_gemm(ctxb, uniAT, uni_b1, Au, M_CNT, 768, 768, false, false, stream);

    int nch = MK_CNT / NC;
    for (int c = 0; c < nch; ++c) {
        int g0 = c * NC;
        launch_fp8_t<2, 0, 0>(candq + (size_t)g0 * D_DIM, wqkvq, bqkv, qkvcb, nullptr, NC, 768, 2304, stream);
        launch_gemm(candb + (size_t)g0 * D_DIM, wruT, nullptr, rucb, NC, 768, 1536, false, true, stream);

        attn_kernel<<<NC, 512, 0, stream>>>(qkvm, qkvcb, obuf, g0);

        launch_fp8_t<2, 0, 0>(obuf, woq, bo, x1pre, nullptr, 2 * NC, 768, 768, stream);
        ln1_kernel<<<2 * NC / 4, 256, 0, stream>>>(x1pre, mention, candb,
                                                   ln1_g, ln1_b, x1f, x1q, g0);

        launch_fp8_t<1, 1, 0>(x1q, w1q, ffn_b1, hb, nullptr, 2 * NC, 768, 3072, stream);
        // FFN2 with fused +x1 residual -> x2f holds LN2 input
        launch_fp8_t<2, 0, 1>(hb, w2q, ffn_b2, x2f, x1f, 2 * NC, 3072, 768, stream);

        heads_kernel<<<NC / 4, 256, 0, stream>>>(x2f, ln2_g, ln2_b, Ar, Au, rucb,
                                                 relik_w2, relik_b2, w2bar, b2bar, out, g0);
    }
}